// Round 1
// baseline (6281.986 us; speedup 1.0000x reference)
//
#include <hip/hip_runtime.h>
#include <hip/hip_bf16.h>
#include <math.h>

// Problem constants
#define BB 256
#define LL 16
#define HH 256
#define VV 5000
#define NPG 150
#define DEG 4
#define NSTEPS 4
#define OUTD 2000
#define NN (BB*NPG)      // 38400
#define EE (BB*NPG*DEG)  // 153600
#define BL (BB*LL)       // 4096
#define CHUNK 1024       // phase-A row chunk

// ---------------- helpers ----------------
__device__ __forceinline__ float wred_sum(float v){
  #pragma unroll
  for(int o=32;o;o>>=1) v += __shfl_down(v,o,64);
  return v;
}
__device__ __forceinline__ float wred_max(float v){
  #pragma unroll
  for(int o=32;o;o>>=1) v = fmaxf(v,__shfl_down(v,o,64));
  return v;
}
__device__ __forceinline__ float block_sum256(float v, float* sh){
  v = wred_sum(v);
  __syncthreads();
  if((threadIdx.x&63)==0) sh[threadIdx.x>>6]=v;
  __syncthreads();
  return sh[0]+sh[1]+sh[2]+sh[3];
}
__device__ __forceinline__ float block_max256(float v, float* sh){
  v = wred_max(v);
  __syncthreads();
  if((threadIdx.x&63)==0) sh[threadIdx.x>>6]=v;
  __syncthreads();
  return fmaxf(fmaxf(sh[0],sh[1]),fmaxf(sh[2],sh[3]));
}
__device__ __forceinline__ float eluf(float x){ return x>0.f ? x : expm1f(x); }
__device__ __forceinline__ float sigf(float x){ return 1.f/(1.f+expf(-x)); }

__device__ __forceinline__ void storeC(float* C, size_t o, float v){ C[o]=v; }
__device__ __forceinline__ void storeC(__hip_bfloat16* C, size_t o, float v){ C[o]=__float2bfloat16(v); }

// ---------------- generic tiled GEMM: C[m,n] = sum_k A[m,k]*B[k,n] (+bias[n]) ----------------
template<typename OUT_T>
__global__ __launch_bounds__(256) void gemm_ab_k(
    const float* __restrict__ A, const float* __restrict__ B, OUT_T* __restrict__ C,
    int M, int N, int K, int lda, int ldb, int ldc,
    const float* __restrict__ bias)
{
  __shared__ __align__(16) float As[16][68];   // [k][m], padded: 68*4B = 16B-mult
  __shared__ __align__(16) float Bs[16][64];   // [k][n]
  const int bm = blockIdx.y*64, bn = blockIdx.x*64;
  const int tid = threadIdx.x;
  const int tx = tid & 15, ty = tid >> 4;
  float acc[4][4] = {};
  for (int k0 = 0; k0 < K; k0 += 16) {
    #pragma unroll
    for (int i=0;i<4;i++){
      int idx = tid + i*256;
      int r = idx >> 4, cc = idx & 15;          // A tile: m=r, k=cc
      int gm = bm + r, gk = k0 + cc;
      As[cc][r] = (gm < M && gk < K) ? A[(size_t)gm*lda + gk] : 0.f;
    }
    #pragma unroll
    for (int i=0;i<4;i++){
      int idx = tid + i*256;
      int r = idx >> 6, cc = idx & 63;          // B tile: k=r, n=cc
      int gk = k0 + r, gn = bn + cc;
      Bs[r][cc] = (gk < K && gn < N) ? B[(size_t)gk*ldb + gn] : 0.f;
    }
    __syncthreads();
    #pragma unroll
    for (int k=0;k<16;k++){
      float4 av = *reinterpret_cast<const float4*>(&As[k][ty*4]);
      float4 bv = *reinterpret_cast<const float4*>(&Bs[k][tx*4]);
      float a[4]={av.x,av.y,av.z,av.w};
      float b[4]={bv.x,bv.y,bv.z,bv.w};
      #pragma unroll
      for(int i=0;i<4;i++)
        #pragma unroll
        for(int j=0;j<4;j++)
          acc[i][j] = fmaf(a[i], b[j], acc[i][j]);
    }
    __syncthreads();
  }
  #pragma unroll
  for(int i=0;i<4;i++){
    int gm = bm + ty*4 + i;
    if (gm >= M) continue;
    #pragma unroll
    for(int j=0;j<4;j++){
      int gn = bn + tx*4 + j;
      if (gn >= N) continue;
      float v = acc[i][j];
      if (bias) v += bias[gn];
      storeC(C, (size_t)gm*ldc + gn, v);
    }
  }
}

// ---------------- small utility kernels ----------------
__global__ void transpose_k(const float* __restrict__ src, float* __restrict__ dst, int R, int Ccols){
  int idx = blockIdx.x*256 + threadIdx.x;
  if (idx >= R*Ccols) return;
  int r = idx / Ccols, c = idx % Ccols;
  dst[(size_t)c*R + r] = src[idx];
}

__global__ void build_ct_k(const float* __restrict__ vocab, const float* __restrict__ de, float* __restrict__ Ct){
  int idx = blockIdx.x*256 + threadIdx.x;
  if (idx >= 256*(VV+1)) return;
  int h = idx / (VV+1), v = idx % (VV+1);
  Ct[idx] = (v < VV) ? vocab[(size_t)v*HH + h] : de[h];
}

__global__ void bsum_k(const float* a, const float* b, float* o){
  int i = blockIdx.x*256 + threadIdx.x;
  if (i < 4*HH) o[i] = a[i] + b[i];
}

__global__ void init_k(float* h, float* c, float* hx, float* dist){
  int idx = blockIdx.x*256 + threadIdx.x;
  if (idx < BB*HH){ h[idx]=0.f; c[idx]=0.f; hx[idx]=0.f; }
  if (idx < NN) dist[idx] = 1.f/150.f;
}

__global__ void zero_k(float* p, int n){
  int idx = blockIdx.x*256 + threadIdx.x;
  if (idx < n) p[idx] = 0.f;
}

// softmax over rows of length Ncols (in place)
__global__ __launch_bounds__(256) void softmax_rows_k(float* __restrict__ X, int Ncols, int ld){
  __shared__ float sh[4];
  float* row = X + (size_t)blockIdx.x*ld;
  float mx = -1e30f;
  for (int i=threadIdx.x; i<Ncols; i+=256) mx = fmaxf(mx, row[i]);
  mx = block_max256(mx, sh);
  float s = 0.f;
  for (int i=threadIdx.x; i<Ncols; i+=256){ float e = expf(row[i]-mx); row[i]=e; s+=e; }
  s = block_sum256(s, sh);
  float inv = 1.f/s;
  for (int i=threadIdx.x; i<Ncols; i+=256) row[i] *= inv;
}

// Vtag[r0+w,h] += Pm[w,V]*words[r0+w,h]
__global__ void vtag_epi_k(float* __restrict__ Vtag, const float* __restrict__ Pm,
                           const float* __restrict__ words, int r0){
  int w = blockIdx.x, h = threadIdx.x;
  float p = Pm[(size_t)w*(VV+1) + VV];
  size_t o = (size_t)(r0+w)*HH + h;
  Vtag[o] += p * words[o];
}

// LSTM cell update for timestep t
__global__ void lstm_update_k(const float* __restrict__ gX, const float* __restrict__ g2,
                              float* __restrict__ h, float* __restrict__ c,
                              const int* __restrict__ lengths, int t){
  int b = blockIdx.x, hh = threadIdx.x;
  int idx = b*HH + hh;
  const float* gx = gX + (size_t)(b*LL + t)*(4*HH);
  const float* gg = g2 + (size_t)b*(4*HH);
  float gi = gx[hh]        + gg[hh];
  float gf = gx[HH+hh]     + gg[HH+hh];
  float gc = gx[2*HH+hh]   + gg[2*HH+hh];
  float go = gx[3*HH+hh]   + gg[3*HH+hh];
  float cn = sigf(gf)*c[idx] + sigf(gi)*tanhf(gc);
  float hn = sigf(go)*tanhf(cn);
  if (t < lengths[b]){ h[idx]=hn; c[idx]=cn; }
}

// decoder update: hx = relu(qproj + g2); Hins[b,s,:] = hx
__global__ void rnn_update_k(const float* __restrict__ qproj, const float* __restrict__ g2,
                             float* __restrict__ hx, float* __restrict__ Hins, int s){
  int b = blockIdx.x, hh = threadIdx.x;
  int idx = b*HH + hh;
  float v = fmaxf(qproj[idx] + g2[idx], 0.f);
  hx[idx] = v;
  Hins[(size_t)b*(NSTEPS*HH) + s*HH + hh] = v;
}

// attention per graph: att = Hins·Vpad^T, masked softmax over L, R = att@Vpad
__global__ __launch_bounds__(256) void attention_k(const float* __restrict__ Vtag,
                                                   const float* __restrict__ Hins,
                                                   const int* __restrict__ lengths,
                                                   float* __restrict__ R){
  __shared__ float Vl[LL][HH];
  __shared__ float Hn[NSTEPS][HH];
  __shared__ float att[NSTEPS][LL];
  int b = blockIdx.x, tid = threadIdx.x;
  for (int idx=tid; idx<LL*HH; idx+=256){ int l=idx>>8, h=idx&255; Vl[l][h] = Vtag[((size_t)b*LL+l)*HH + h]; }
  for (int idx=tid; idx<NSTEPS*HH; idx+=256){ Hn[idx>>8][idx&255] = Hins[(size_t)b*(NSTEPS*HH) + idx]; }
  __syncthreads();
  if (tid < NSTEPS*LL){
    int n2 = tid>>4, l = tid&15;
    float s = 0.f;
    for (int k=0;k<HH;k++) s += Hn[n2][k]*Vl[l][k];
    att[n2][l] = s;
  }
  __syncthreads();
  int len = lengths[b];
  if (tid < NSTEPS){
    float m = -1e30f;
    for (int l=0;l<len;l++) m = fmaxf(m, att[tid][l]);
    float s = 0.f;
    for (int l=0;l<LL;l++){ float e = (l<len)? expf(att[tid][l]-m) : 0.f; att[tid][l]=e; s+=e; }
    float inv = 1.f/s;
    for (int l=0;l<LL;l++) att[tid][l] *= inv;
  }
  __syncthreads();
  {
    int n2 = tid>>6, h0 = (tid&63)*4;
    float r0=0,r1=0,r2=0,r3=0;
    for (int l=0;l<LL;l++){
      float w = att[n2][l];
      r0 += w*Vl[l][h0]; r1 += w*Vl[l][h0+1]; r2 += w*Vl[l][h0+2]; r3 += w*Vl[l][h0+3];
    }
    float* o = R + (size_t)b*(NSTEPS*HH) + n2*HH + h0;
    o[0]=r0; o[1]=r1; o[2]=r2; o[3]=r3;
  }
}

// prop_sim[b,:] = softmax_p( instr[b]·prop_embeds[p] )
__global__ __launch_bounds__(256) void prop_sim_k(const float* __restrict__ R, const float* __restrict__ pe,
                                                  float* __restrict__ ps, int step){
  __shared__ float sp[4];
  int b = blockIdx.x, tid = threadIdx.x;
  int p = tid>>6, lane = tid&63;
  const float* instr = R + (size_t)b*(NSTEPS*HH) + step*HH;
  float v = 0.f;
  for (int h=lane; h<HH; h+=64) v += instr[h]*pe[p*HH+h];
  v = wred_sum(v);
  if (lane==0) sp[p] = v;
  __syncthreads();
  if (tid==0){
    float m = fmaxf(fmaxf(sp[0],sp[1]),fmaxf(sp[2],sp[3]));
    float e0=expf(sp[0]-m), e1=expf(sp[1]-m), e2=expf(sp[2]-m), e3=expf(sp[3]-m);
    float s = e0+e1+e2+e3;
    ps[b*4+0]=e0/s; ps[b*4+1]=e1/s; ps[b*4+2]=e2/s; ps[b*4+3]=e3/s;
  }
}

// s_state[n] = sum_h elu(instr[g,h] * sum_p ps[g,p]*T[n,p,h]) * W_state[h]
__global__ __launch_bounds__(256) void node_state_k(const __hip_bfloat16* __restrict__ T,
                                                    const float* __restrict__ R,
                                                    const float* __restrict__ ps,
                                                    const float* __restrict__ W_state,
                                                    float* __restrict__ s_state, int step){
  __shared__ float sh[4];
  int n = blockIdx.x, h = threadIdx.x;
  int g = n / NPG;
  const float* instr = R + (size_t)g*(NSTEPS*HH) + step*HH;
  float ps0 = ps[g*4+0], ps1 = ps[g*4+1], ps2 = ps[g*4+2];
  const __hip_bfloat16* t = T + (size_t)n*(3*HH);
  float tv = ps0*__bfloat162float(t[h]) + ps1*__bfloat162float(t[HH+h]) + ps2*__bfloat162float(t[2*HH+h]);
  float v = eluf(instr[h]*tv) * W_state[h];
  float s = block_sum256(v, sh);
  if (h==0) s_state[n] = s;
}

// segment softmax over contiguous segments of 150
__global__ __launch_bounds__(256) void seg_softmax_k(const float* __restrict__ x, float* __restrict__ y){
  __shared__ float sh[4];
  int b = blockIdx.x, i = threadIdx.x;
  float v = (i < NPG) ? x[b*NPG + i] : -1e30f;
  float m = block_max256(v, sh);
  float e = (i < NPG) ? expf(v - m) : 0.f;
  float s = block_sum256(e, sh);
  if (i < NPG) y[b*NPG + i] = e / s;
}

// scatter: agg[dst,h] += dist[src] * elu(instr[b,h]*edgeT[e,h])
__global__ __launch_bounds__(256) void edge_scatter_k(const __hip_bfloat16* __restrict__ ET,
                                                      const float* __restrict__ R,
                                                      const float* __restrict__ dist,
                                                      const int* __restrict__ esrc,
                                                      const int* __restrict__ edst,
                                                      float* __restrict__ agg, int step){
  int e = blockIdx.x, h = threadIdx.x;
  int b = e / (NPG*DEG);
  const float* instr = R + (size_t)b*(NSTEPS*HH) + step*HH;
  float d = dist[esrc[e]];
  float v = eluf(instr[h] * __bfloat162float(ET[(size_t)e*HH + h])) * d;
  atomicAdd(&agg[(size_t)edst[e]*HH + h], v);
}

// s_rel[n] = agg[n]·W_relation
__global__ __launch_bounds__(256) void srel_k(const float* __restrict__ agg, const float* __restrict__ Wr,
                                              float* __restrict__ s_rel){
  __shared__ float sh[4];
  int n = blockIdx.x, h = threadIdx.x;
  float v = agg[(size_t)n*HH + h] * Wr[h];
  float s = block_sum256(v, sh);
  if (h==0) s_rel[n] = s;
}

__global__ void dist_update_k(const float* __restrict__ ps, const float* __restrict__ p_rel,
                              const float* __restrict__ p_state, float* __restrict__ dist){
  int n = blockIdx.x*256 + threadIdx.x;
  if (n >= NN) return;
  int g = n / NPG;
  float r = ps[g*4+3];
  dist[n] = r*p_rel[n] + (1.f-r)*p_state[n];
}

// aggregated[b,h] = sum_{n in b} dist[n] * sum_p ps[b,p]*na[n,p,h]
__global__ __launch_bounds__(256) void final_agg_k(const float* __restrict__ na, const float* __restrict__ dist,
                                                   const float* __restrict__ ps, float* __restrict__ aggregated){
  int b = blockIdx.x, h = threadIdx.x;
  float ps0 = ps[b*4+0], ps1 = ps[b*4+1], ps2 = ps[b*4+2];
  float acc = 0.f;
  for (int i=0;i<NPG;i++){
    int n = b*NPG + i;
    float d = dist[n];
    const float* a = na + (size_t)n*(3*HH);
    acc += d*(ps0*a[h] + ps1*a[HH+h] + ps2*a[2*HH+h]);
  }
  aggregated[b*HH + h] = acc;
}

__global__ void qa_build_k(const float* __restrict__ Q, const float* __restrict__ aggregated,
                           float* __restrict__ QA){
  int idx = blockIdx.x*256 + threadIdx.x;
  if (idx >= BB*2*HH) return;
  int b = idx >> 9, k = idx & 511;
  QA[idx] = (k < HH) ? Q[b*HH + k] : aggregated[b*HH + (k-HH)];
}

// ---------------- host ----------------
static inline void gemm_f32(hipStream_t s, const float* A, const float* B, float* C,
                            int M, int N, int K, int lda, int ldb, int ldc, const float* bias){
  dim3 g((N+63)/64, (M+63)/64);
  gemm_ab_k<float><<<g, 256, 0, s>>>(A,B,C,M,N,K,lda,ldb,ldc,bias);
}
static inline void gemm_bf16(hipStream_t s, const float* A, const float* B, __hip_bfloat16* C,
                             int M, int N, int K, int lda, int ldb, int ldc){
  dim3 g((N+63)/64, (M+63)/64);
  gemm_ab_k<__hip_bfloat16><<<g, 256, 0, s>>>(A,B,C,M,N,K,lda,ldb,ldc,nullptr);
}

extern "C" void kernel_launch(void* const* d_in, const int* in_sizes, int n_in,
                              void* d_out, int out_size, void* d_ws, size_t ws_size,
                              hipStream_t stream) {
  (void)in_sizes; (void)n_in; (void)out_size; (void)ws_size;
  const float* questions     = (const float*)d_in[0];   // (B,L,H) == words (BL,H)
  const float* node_attrs    = (const float*)d_in[1];   // (N,3,H)
  const float* edge_attrs    = (const float*)d_in[2];   // (E,H)
  const float* vocab         = (const float*)d_in[3];   // (V,H)
  const float* default_embed = (const float*)d_in[4];   // (H,)
  const float* W_norm        = (const float*)d_in[5];   // (H,H)
  const float* lstm_Wih      = (const float*)d_in[6];   // (4H,H)
  const float* lstm_Whh      = (const float*)d_in[7];
  const float* lstm_bih      = (const float*)d_in[8];
  const float* lstm_bhh      = (const float*)d_in[9];
  const float* rnn_Wih       = (const float*)d_in[10];  // (H,H)
  const float* rnn_Whh       = (const float*)d_in[11];
  const float* rnn_bih       = (const float*)d_in[12];
  const float* rnn_bhh       = (const float*)d_in[13];
  const float* prop_embeds   = (const float*)d_in[14];  // (4,H)
  const float* Ws_property   = (const float*)d_in[15];  // (4,H,H)
  const float* W_state       = (const float*)d_in[16];
  const float* W_relation    = (const float*)d_in[17];
  const float* lin_W         = (const float*)d_in[18];  // (OUT,2H)
  const float* lin_b         = (const float*)d_in[19];
  const int*   lengths       = (const int*)d_in[20];
  const int*   edge_src      = (const int*)d_in[23];
  const int*   edge_dst      = (const int*)d_in[24];
  float* out = (float*)d_out;

  char* base = (char*)d_ws;
  size_t off = 0;
  auto alloc = [&](size_t nbytes)->void*{
    void* p = base + off;
    off += (nbytes + 255) & ~(size_t)255;
    return p;
  };

  float* xw       = (float*)alloc((size_t)BL*HH*4);
  float* Ct       = (float*)alloc((size_t)HH*(VV+1)*4);
  float* Vtag     = (float*)alloc((size_t)BL*HH*4);
  float* WihT     = (float*)alloc((size_t)HH*4*HH*4);
  float* WhhT     = (float*)alloc((size_t)HH*4*HH*4);
  float* bsum     = (float*)alloc((size_t)4*HH*4);
  float* rWihT    = (float*)alloc((size_t)HH*HH*4);
  float* rWhhT    = (float*)alloc((size_t)HH*HH*4);
  float* WpT      = (float*)alloc((size_t)4*HH*HH*4);
  float* linWT    = (float*)alloc((size_t)2*HH*OUTD*4);
  float* gX       = (float*)alloc((size_t)BL*4*HH*4);
  float* g2       = (float*)alloc((size_t)BB*4*HH*4);
  float* h_buf    = (float*)alloc((size_t)BB*HH*4);
  float* c_buf    = (float*)alloc((size_t)BB*HH*4);
  float* qproj    = (float*)alloc((size_t)BB*HH*4);
  float* hx       = (float*)alloc((size_t)BB*HH*4);
  float* Hins     = (float*)alloc((size_t)BB*NSTEPS*HH*4);
  float* R        = (float*)alloc((size_t)BB*NSTEPS*HH*4);
  __hip_bfloat16* Tf = (__hip_bfloat16*)alloc((size_t)NN*3*HH*2);
  __hip_bfloat16* ET = (__hip_bfloat16*)alloc((size_t)EE*HH*2);
  float* prop_sim = (float*)alloc((size_t)BB*4*4);
  float* s_state  = (float*)alloc((size_t)NN*4);
  float* p_state  = (float*)alloc((size_t)NN*4);
  float* s_rel    = (float*)alloc((size_t)NN*4);
  float* p_rel    = (float*)alloc((size_t)NN*4);
  float* dist     = (float*)alloc((size_t)NN*4);
  float* aggregated = (float*)alloc((size_t)BB*HH*4);
  float* QA       = (float*)alloc((size_t)BB*2*HH*4);
  // union region: phase-A chunk buffer (1024x5001 f32 = 20.5MB) aliases agg (N*H f32 = 39.3MB)
  float* bigbuf   = (float*)alloc((size_t)NN*HH*4);
  float* Pmbuf = bigbuf;
  float* agg   = bigbuf;

  // ---- setup: transposes / init ----
  init_k<<<256, 256, 0, stream>>>(h_buf, c_buf, hx, dist);
  transpose_k<<<(4*HH*HH+255)/256, 256, 0, stream>>>(lstm_Wih, WihT, 4*HH, HH);
  transpose_k<<<(4*HH*HH+255)/256, 256, 0, stream>>>(lstm_Whh, WhhT, 4*HH, HH);
  transpose_k<<<(HH*HH+255)/256, 256, 0, stream>>>(rnn_Wih, rWihT, HH, HH);
  transpose_k<<<(HH*HH+255)/256, 256, 0, stream>>>(rnn_Whh, rWhhT, HH, HH);
  for (int p=0; p<4; p++)
    transpose_k<<<(HH*HH+255)/256, 256, 0, stream>>>(Ws_property + (size_t)p*HH*HH, WpT + (size_t)p*HH*HH, HH, HH);
  transpose_k<<<(OUTD*2*HH+255)/256, 256, 0, stream>>>(lin_W, linWT, OUTD, 2*HH);
  bsum_k<<<(4*HH+255)/256, 256, 0, stream>>>(lstm_bih, lstm_bhh, bsum);
  build_ct_k<<<(HH*(VV+1)+255)/256, 256, 0, stream>>>(vocab, default_embed, Ct);

  // ---- phase A: word embedding (chunked softmax over V+1) ----
  gemm_f32(stream, questions, W_norm, xw, BL, HH, HH, HH, HH, HH, nullptr);
  for (int c=0; c<BL/CHUNK; c++){
    int r0 = c*CHUNK;
    gemm_f32(stream, xw + (size_t)r0*HH, Ct, Pmbuf, CHUNK, VV+1, HH, HH, VV+1, VV+1, nullptr);
    softmax_rows_k<<<CHUNK, 256, 0, stream>>>(Pmbuf, VV+1, VV+1);
    gemm_f32(stream, Pmbuf, vocab, Vtag + (size_t)r0*HH, CHUNK, HH, VV, VV+1, HH, HH, nullptr);
    vtag_epi_k<<<CHUNK, 256, 0, stream>>>(Vtag, Pmbuf, questions, r0);
  }

  // ---- phase B: LSTM encoder ----
  gemm_f32(stream, Vtag, WihT, gX, BL, 4*HH, HH, HH, 4*HH, 4*HH, bsum);
  for (int t=0; t<LL; t++){
    gemm_f32(stream, h_buf, WhhT, g2, BB, 4*HH, HH, HH, 4*HH, 4*HH, nullptr);
    lstm_update_k<<<BB, HH, 0, stream>>>(gX, g2, h_buf, c_buf, lengths, t);
  }

  // ---- phase C: decoder RNN ----
  gemm_f32(stream, h_buf, rWihT, qproj, BB, HH, HH, HH, HH, HH, rnn_bih);
  for (int s=0; s<NSTEPS; s++){
    gemm_f32(stream, hx, rWhhT, g2, BB, HH, HH, HH, HH, HH, rnn_bhh);
    rnn_update_k<<<BB, HH, 0, stream>>>(qproj, g2, hx, Hins, s);
  }

  // ---- phase D: attention -> R ----
  attention_k<<<BB, 256, 0, stream>>>(Vtag, Hins, lengths, R);

  // ---- phase E: step-invariant heavy GEMMs (bf16 out) ----
  for (int p=0; p<3; p++)
    gemm_bf16(stream, node_attrs + (size_t)p*HH, WpT + (size_t)p*HH*HH,
              Tf + (size_t)p*HH, NN, HH, HH, 3*HH, HH, 3*HH);
  gemm_bf16(stream, edge_attrs, WpT + (size_t)3*HH*HH, ET, EE, HH, HH, HH, HH, HH);

  // ---- phase F: 4-step NSM loop ----
  for (int s=0; s<NSTEPS; s++){
    prop_sim_k<<<BB, 256, 0, stream>>>(R, prop_embeds, prop_sim, s);
    node_state_k<<<NN, 256, 0, stream>>>(Tf, R, prop_sim, W_state, s_state, s);
    seg_softmax_k<<<BB, 256, 0, stream>>>(s_state, p_state);
    zero_k<<<(NN*HH+255)/256, 256, 0, stream>>>(agg, NN*HH);
    edge_scatter_k<<<EE, 256, 0, stream>>>(ET, R, dist, edge_src, edge_dst, agg, s);
    srel_k<<<NN, 256, 0, stream>>>(agg, W_relation, s_rel);
    seg_softmax_k<<<BB, 256, 0, stream>>>(s_rel, p_rel);
    dist_update_k<<<(NN+255)/256, 256, 0, stream>>>(prop_sim, p_rel, p_state, dist);
  }

  // ---- phase G: readout ----
  final_agg_k<<<BB, 256, 0, stream>>>(node_attrs, dist, prop_sim, aggregated);
  qa_build_k<<<(BB*2*HH+255)/256, 256, 0, stream>>>(h_buf, aggregated, QA);
  gemm_f32(stream, QA, linWT, out, BB, OUTD, 2*HH, 2*HH, OUTD, OUTD, lin_b);
}

// Round 2
// 2335.735 us; speedup vs baseline: 2.6895x; 2.6895x over previous
//
#include <hip/hip_runtime.h>
#include <hip/hip_bf16.h>
#include <math.h>

// Problem constants
#define BB 256
#define LL 16
#define HH 256
#define VV 5000
#define NPG 150
#define DEG 4
#define NSTEPS 4
#define OUTD 2000
#define NN (BB*NPG)      // 38400
#define EE (BB*NPG*DEG)  // 153600
#define BL (BB*LL)       // 4096
#define CHUNK 1024       // phase-A row chunk
#define VPAD 5120        // logits column pad (40*128)
#define KPAD 5024        // Pm K pad (157*32)

// ---------------- helpers ----------------
__device__ __forceinline__ float wred_sum(float v){
  #pragma unroll
  for(int o=32;o;o>>=1) v += __shfl_down(v,o,64);
  return v;
}
__device__ __forceinline__ float wred_max(float v){
  #pragma unroll
  for(int o=32;o;o>>=1) v = fmaxf(v,__shfl_down(v,o,64));
  return v;
}
__device__ __forceinline__ float block_sum256(float v, float* sh){
  v = wred_sum(v);
  __syncthreads();
  if((threadIdx.x&63)==0) sh[threadIdx.x>>6]=v;
  __syncthreads();
  return sh[0]+sh[1]+sh[2]+sh[3];
}
__device__ __forceinline__ float block_max256(float v, float* sh){
  v = wred_max(v);
  __syncthreads();
  if((threadIdx.x&63)==0) sh[threadIdx.x>>6]=v;
  __syncthreads();
  return fmaxf(fmaxf(sh[0],sh[1]),fmaxf(sh[2],sh[3]));
}
__device__ __forceinline__ float eluf(float x){ return x>0.f ? x : expm1f(x); }
__device__ __forceinline__ float sigf(float x){ return 1.f/(1.f+expf(-x)); }

// async global->LDS 16B (gfx950), lds dest = wave-uniform base + lane*16
__device__ __forceinline__ void async16(void* lds, const void* g){
  __builtin_amdgcn_global_load_lds(
      (const __attribute__((address_space(1))) unsigned int*)g,
      (__attribute__((address_space(3))) unsigned int*)lds, 16, 0, 0);
}

typedef __attribute__((ext_vector_type(8))) short short8;
typedef __attribute__((ext_vector_type(4))) float f32x4;

// =======================================================================
// MFMA GEMM, C[m,n] = sum_k A[m,k]*Bt[n,k].  128x128 tile, BK=32, 4 waves.
// EPI: 0 = f32 store (+bias, col<Nreal), 1 = bf16 store, 2 = f32 atomicAdd
// =======================================================================
template<int EPI>
__global__ __launch_bounds__(256) void mfma_bt_bf16_k(
    const __hip_bfloat16* __restrict__ A, const __hip_bfloat16* __restrict__ Bt,
    float* __restrict__ Cf, __hip_bfloat16* __restrict__ Cb,
    int lda, int ldb, int ldc, int Nreal,
    int kItersTotal, int kPerSplit, const float* __restrict__ bias)
{
  __shared__ __hip_bfloat16 As[128*32];
  __shared__ __hip_bfloat16 Bs[128*32];
  const int bm = blockIdx.y*128, bn = blockIdx.x*128;
  const int tid = threadIdx.x;
  int k0 = blockIdx.z * kPerSplit;
  int k1 = k0 + kPerSplit; if (k1 > kItersTotal) k1 = kItersTotal;
  const int lane = tid & 63, wave = tid >> 6;
  const int quad = lane >> 4, r16 = lane & 15;
  const int wr = wave >> 1, wc = wave & 1;
  f32x4 acc[4][4] = {};
  const int c0 = tid, c1 = tid + 256;
  const int ar0 = c0 >> 2, ak0 = (c0 & 3)*8;
  const int ar1 = c1 >> 2, ak1 = (c1 & 3)*8;
  const __hip_bfloat16* Ab = A + (size_t)bm*lda;
  const __hip_bfloat16* Bb = Bt + (size_t)bn*ldb;
  for (int kk = k0; kk < k1; ++kk){
    const int kb = kk*32;
    async16(&As[c0*8], Ab + (size_t)ar0*lda + kb + ak0);
    async16(&As[c1*8], Ab + (size_t)ar1*lda + kb + ak1);
    async16(&Bs[c0*8], Bb + (size_t)ar0*ldb + kb + ak0);
    async16(&Bs[c1*8], Bb + (size_t)ar1*ldb + kb + ak1);
    __syncthreads();
    short8 av[4], bv[4];
    #pragma unroll
    for (int i=0;i<4;i++){
      av[i] = *(const short8*)&As[(wr*64 + i*16 + r16)*32 + quad*8];
      bv[i] = *(const short8*)&Bs[(wc*64 + i*16 + r16)*32 + quad*8];
    }
    #pragma unroll
    for (int i=0;i<4;i++)
      #pragma unroll
      for (int j=0;j<4;j++)
        acc[i][j] = __builtin_amdgcn_mfma_f32_16x16x32_bf16(av[i], bv[j], acc[i][j], 0,0,0);
    __syncthreads();
  }
  #pragma unroll
  for (int i=0;i<4;i++){
    int row = bm + wr*64 + i*16 + quad*4;
    #pragma unroll
    for (int j=0;j<4;j++){
      int col = bn + wc*64 + j*16 + r16;
      if (col >= Nreal) continue;
      #pragma unroll
      for (int r=0;r<4;r++){
        float v = acc[i][j][r];
        if (EPI==0){ if (bias) v += bias[col]; Cf[(size_t)(row+r)*ldc + col] = v; }
        else if (EPI==1){ Cb[(size_t)(row+r)*ldc + col] = __float2bfloat16(v); }
        else { atomicAdd(&Cf[(size_t)(row+r)*ldc + col], v); }
      }
    }
  }
}

// Same GEMM but f32 global operands, converted to bf16 during VALU staging.
template<int EPI>
__global__ __launch_bounds__(256) void mfma_bt_f32_k(
    const float* __restrict__ A, const float* __restrict__ Bt,
    float* __restrict__ Cf, __hip_bfloat16* __restrict__ Cb,
    int lda, int ldb, int ldc, int Nreal,
    int kIters, const float* __restrict__ bias)
{
  __shared__ __hip_bfloat16 As[128*32];
  __shared__ __hip_bfloat16 Bs[128*32];
  const int bm = blockIdx.y*128, bn = blockIdx.x*128;
  const int tid = threadIdx.x;
  const int lane = tid & 63, wave = tid >> 6;
  const int quad = lane >> 4, r16 = lane & 15;
  const int wr = wave >> 1, wc = wave & 1;
  f32x4 acc[4][4] = {};
  for (int kk = 0; kk < kIters; ++kk){
    const int kb = kk*32;
    #pragma unroll
    for (int i=0;i<4;i++){
      int c = tid + i*256;
      int row = c >> 3, kc = (c & 7)*4;
      float4 v = *(const float4*)(A + (size_t)(bm+row)*lda + kb + kc);
      As[row*32+kc]   = __float2bfloat16(v.x);
      As[row*32+kc+1] = __float2bfloat16(v.y);
      As[row*32+kc+2] = __float2bfloat16(v.z);
      As[row*32+kc+3] = __float2bfloat16(v.w);
    }
    #pragma unroll
    for (int i=0;i<4;i++){
      int c = tid + i*256;
      int row = c >> 3, kc = (c & 7)*4;
      float4 v = {0.f,0.f,0.f,0.f};
      if (bn + row < Nreal) v = *(const float4*)(Bt + (size_t)(bn+row)*ldb + kb + kc);
      Bs[row*32+kc]   = __float2bfloat16(v.x);
      Bs[row*32+kc+1] = __float2bfloat16(v.y);
      Bs[row*32+kc+2] = __float2bfloat16(v.z);
      Bs[row*32+kc+3] = __float2bfloat16(v.w);
    }
    __syncthreads();
    short8 av[4], bv[4];
    #pragma unroll
    for (int i=0;i<4;i++){
      av[i] = *(const short8*)&As[(wr*64 + i*16 + r16)*32 + quad*8];
      bv[i] = *(const short8*)&Bs[(wc*64 + i*16 + r16)*32 + quad*8];
    }
    #pragma unroll
    for (int i=0;i<4;i++)
      #pragma unroll
      for (int j=0;j<4;j++)
        acc[i][j] = __builtin_amdgcn_mfma_f32_16x16x32_bf16(av[i], bv[j], acc[i][j], 0,0,0);
    __syncthreads();
  }
  #pragma unroll
  for (int i=0;i<4;i++){
    int row = bm + wr*64 + i*16 + quad*4;
    #pragma unroll
    for (int j=0;j<4;j++){
      int col = bn + wc*64 + j*16 + r16;
      if (col >= Nreal) continue;
      #pragma unroll
      for (int r=0;r<4;r++){
        float v = acc[i][j][r];
        if (EPI==0){ if (bias) v += bias[col]; Cf[(size_t)(row+r)*ldc + col] = v; }
        else { Cb[(size_t)(row+r)*ldc + col] = __float2bfloat16(v); }
      }
    }
  }
}

// ---------------- fp32 SIMD GEMM (kept for small LSTM/decoder steps) ----------------
__global__ __launch_bounds__(256) void gemm_ab_k(
    const float* __restrict__ A, const float* __restrict__ B, float* __restrict__ C,
    int M, int N, int K, int lda, int ldb, int ldc,
    const float* __restrict__ bias)
{
  __shared__ __align__(16) float Asf[16][68];
  __shared__ __align__(16) float Bsf[16][64];
  const int bm = blockIdx.y*64, bn = blockIdx.x*64;
  const int tid = threadIdx.x;
  const int tx = tid & 15, ty = tid >> 4;
  float acc[4][4] = {};
  for (int k0 = 0; k0 < K; k0 += 16) {
    #pragma unroll
    for (int i=0;i<4;i++){
      int idx = tid + i*256;
      int r = idx >> 4, cc = idx & 15;
      int gm = bm + r, gk = k0 + cc;
      Asf[cc][r] = (gm < M && gk < K) ? A[(size_t)gm*lda + gk] : 0.f;
    }
    #pragma unroll
    for (int i=0;i<4;i++){
      int idx = tid + i*256;
      int r = idx >> 6, cc = idx & 63;
      int gk = k0 + r, gn = bn + cc;
      Bsf[r][cc] = (gk < K && gn < N) ? B[(size_t)gk*ldb + gn] : 0.f;
    }
    __syncthreads();
    #pragma unroll
    for (int k=0;k<16;k++){
      float4 avv = *reinterpret_cast<const float4*>(&Asf[k][ty*4]);
      float4 bvv = *reinterpret_cast<const float4*>(&Bsf[k][tx*4]);
      float a[4]={avv.x,avv.y,avv.z,avv.w};
      float b[4]={bvv.x,bvv.y,bvv.z,bvv.w};
      #pragma unroll
      for(int i=0;i<4;i++)
        #pragma unroll
        for(int j=0;j<4;j++)
          acc[i][j] = fmaf(a[i], b[j], acc[i][j]);
    }
    __syncthreads();
  }
  #pragma unroll
  for(int i=0;i<4;i++){
    int gm = bm + ty*4 + i;
    if (gm >= M) continue;
    #pragma unroll
    for(int j=0;j<4;j++){
      int gn = bn + tx*4 + j;
      if (gn >= N) continue;
      float v = acc[i][j];
      if (bias) v += bias[gn];
      C[(size_t)gm*ldc + gn] = v;
    }
  }
}

// ---------------- small utility kernels ----------------
__global__ void transpose_k(const float* __restrict__ src, float* __restrict__ dst, int R, int Ccols){
  int idx = blockIdx.x*256 + threadIdx.x;
  if (idx >= R*Ccols) return;
  int r = idx / Ccols, c = idx % Ccols;
  dst[(size_t)c*R + r] = src[idx];
}

__global__ void cvt_bf16_k(const float* __restrict__ src, __hip_bfloat16* __restrict__ dst, int n){
  int i = (blockIdx.x*256 + threadIdx.x)*4;
  if (i >= n) return;
  float4 v = *(const float4*)(src + i);
  dst[i]   = __float2bfloat16(v.x);
  dst[i+1] = __float2bfloat16(v.y);
  dst[i+2] = __float2bfloat16(v.z);
  dst[i+3] = __float2bfloat16(v.w);
}

// WnT_bf[n][k] = W_norm[k][n]
__global__ void tr_cvt_k(const float* __restrict__ src, __hip_bfloat16* __restrict__ dst, int R, int Ccols){
  int idx = blockIdx.x*256 + threadIdx.x;
  if (idx >= R*Ccols) return;
  int r = idx / Ccols, c = idx % Ccols;
  dst[(size_t)c*R + r] = __float2bfloat16(src[idx]);
}

// Cb: 5120 x 256 bf16 rows: [vocab(5000); default(1); zeros(119)]
__global__ void build_cb_k(const float* __restrict__ vocab, const float* __restrict__ de,
                           __hip_bfloat16* __restrict__ Cb){
  int idx = blockIdx.x*256 + threadIdx.x;
  if (idx >= VPAD*HH) return;
  int v = idx >> 8, h = idx & 255;
  float x = (v < VV) ? vocab[(size_t)v*HH + h] : (v == VV ? de[h] : 0.f);
  Cb[idx] = __float2bfloat16(x);
}

// vocabT_bf: 256 x 5024 bf16, vocabT[h][v] = vocab[v][h], pad v>=5000 = 0
__global__ void build_vt_k(const float* __restrict__ vocab, __hip_bfloat16* __restrict__ VT){
  int idx = blockIdx.x*256 + threadIdx.x;
  if (idx >= HH*KPAD) return;
  int h = idx / KPAD, v = idx % KPAD;
  VT[idx] = __float2bfloat16(v < VV ? vocab[(size_t)v*HH + h] : 0.f);
}

__global__ void bsum_k(const float* a, const float* b, float* o){
  int i = blockIdx.x*256 + threadIdx.x;
  if (i < 4*HH) o[i] = a[i] + b[i];
}

__global__ void init_k(float* h, float* c, float* hx, float* dist){
  int idx = blockIdx.x*256 + threadIdx.x;
  if (idx < BB*HH){ h[idx]=0.f; c[idx]=0.f; hx[idx]=0.f; }
  if (idx < NN) dist[idx] = 1.f/150.f;
}

__global__ void zero_k(float* p, int n){
  int idx = blockIdx.x*256 + threadIdx.x;
  if (idx < n) p[idx] = 0.f;
}

// softmax over 5001 valid logits (ld VPAD) -> bf16 Pm row (ld KPAD) + pm_def
__global__ __launch_bounds__(256) void softmax_pm_k(const float* __restrict__ logits,
                                                    __hip_bfloat16* __restrict__ Pm,
                                                    float* __restrict__ pm_def, int r0){
  __shared__ float sh[4];
  int r = blockIdx.x;
  const float* row = logits + (size_t)r*VPAD;
  float mx = -1e30f;
  for (int i=threadIdx.x; i<VV+1; i+=256) mx = fmaxf(mx, row[i]);
  mx = block_max256(mx, sh);
  float s = 0.f;
  for (int i=threadIdx.x; i<VV+1; i+=256) s += expf(row[i]-mx);
  s = block_sum256(s, sh);
  float inv = 1.f/s;
  __hip_bfloat16* prow = Pm + (size_t)(r0+r)*KPAD;
  for (int i=threadIdx.x; i<KPAD; i+=256){
    float p = (i < VV) ? expf(row[i]-mx)*inv : 0.f;
    prow[i] = __float2bfloat16(p);
  }
  if (threadIdx.x==0) pm_def[r0+r] = expf(row[VV]-mx)*inv;
}

// Vtag[r,h] += pm_def[r]*words[r,h]   (full range)
__global__ void vtag_epi_k(float* __restrict__ Vtag, const float* __restrict__ pm_def,
                           const float* __restrict__ words){
  int r = blockIdx.x, h = threadIdx.x;
  size_t o = (size_t)r*HH + h;
  Vtag[o] += pm_def[r] * words[o];
}

// LSTM cell update for timestep t
__global__ void lstm_update_k(const float* __restrict__ gX, const float* __restrict__ g2,
                              float* __restrict__ h, float* __restrict__ c,
                              const int* __restrict__ lengths, int t){
  int b = blockIdx.x, hh = threadIdx.x;
  int idx = b*HH + hh;
  const float* gx = gX + (size_t)(b*LL + t)*(4*HH);
  const float* gg = g2 + (size_t)b*(4*HH);
  float gi = gx[hh]        + gg[hh];
  float gf = gx[HH+hh]     + gg[HH+hh];
  float gc = gx[2*HH+hh]   + gg[2*HH+hh];
  float go = gx[3*HH+hh]   + gg[3*HH+hh];
  float cn = sigf(gf)*c[idx] + sigf(gi)*tanhf(gc);
  float hn = sigf(go)*tanhf(cn);
  if (t < lengths[b]){ h[idx]=hn; c[idx]=cn; }
}

__global__ void rnn_update_k(const float* __restrict__ qproj, const float* __restrict__ g2,
                             float* __restrict__ hx, float* __restrict__ Hins, int s){
  int b = blockIdx.x, hh = threadIdx.x;
  int idx = b*HH + hh;
  float v = fmaxf(qproj[idx] + g2[idx], 0.f);
  hx[idx] = v;
  Hins[(size_t)b*(NSTEPS*HH) + s*HH + hh] = v;
}

// attention per graph
__global__ __launch_bounds__(256) void attention_k(const float* __restrict__ Vtag,
                                                   const float* __restrict__ Hins,
                                                   const int* __restrict__ lengths,
                                                   float* __restrict__ R){
  __shared__ float Vl[LL][HH];
  __shared__ float Hn[NSTEPS][HH];
  __shared__ float att[NSTEPS][LL];
  int b = blockIdx.x, tid = threadIdx.x;
  for (int idx=tid; idx<LL*HH; idx+=256){ int l=idx>>8, h=idx&255; Vl[l][h] = Vtag[((size_t)b*LL+l)*HH + h]; }
  for (int idx=tid; idx<NSTEPS*HH; idx+=256){ Hn[idx>>8][idx&255] = Hins[(size_t)b*(NSTEPS*HH) + idx]; }
  __syncthreads();
  if (tid < NSTEPS*LL){
    int n2 = tid>>4, l = tid&15;
    float s = 0.f;
    for (int k=0;k<HH;k++) s += Hn[n2][k]*Vl[l][k];
    att[n2][l] = s;
  }
  __syncthreads();
  int len = lengths[b];
  if (tid < NSTEPS){
    float m = -1e30f;
    for (int l=0;l<len;l++) m = fmaxf(m, att[tid][l]);
    float s = 0.f;
    for (int l=0;l<LL;l++){ float e = (l<len)? expf(att[tid][l]-m) : 0.f; att[tid][l]=e; s+=e; }
    float inv = 1.f/s;
    for (int l=0;l<LL;l++) att[tid][l] *= inv;
  }
  __syncthreads();
  {
    int n2 = tid>>6, h0 = (tid&63)*4;
    float r0=0,r1=0,r2=0,r3=0;
    for (int l=0;l<LL;l++){
      float w = att[n2][l];
      r0 += w*Vl[l][h0]; r1 += w*Vl[l][h0+1]; r2 += w*Vl[l][h0+2]; r3 += w*Vl[l][h0+3];
    }
    float* o = R + (size_t)b*(NSTEPS*HH) + n2*HH + h0;
    o[0]=r0; o[1]=r1; o[2]=r2; o[3]=r3;
  }
}

__global__ __launch_bounds__(256) void prop_sim_k(const float* __restrict__ R, const float* __restrict__ pe,
                                                  float* __restrict__ ps, int step){
  __shared__ float sp[4];
  int b = blockIdx.x, tid = threadIdx.x;
  int p = tid>>6, lane = tid&63;
  const float* instr = R + (size_t)b*(NSTEPS*HH) + step*HH;
  float v = 0.f;
  for (int h=lane; h<HH; h+=64) v += instr[h]*pe[p*HH+h];
  v = wred_sum(v);
  if (lane==0) sp[p] = v;
  __syncthreads();
  if (tid==0){
    float m = fmaxf(fmaxf(sp[0],sp[1]),fmaxf(sp[2],sp[3]));
    float e0=expf(sp[0]-m), e1=expf(sp[1]-m), e2=expf(sp[2]-m), e3=expf(sp[3]-m);
    float s = e0+e1+e2+e3;
    ps[b*4+0]=e0/s; ps[b*4+1]=e1/s; ps[b*4+2]=e2/s; ps[b*4+3]=e3/s;
  }
}

__global__ __launch_bounds__(256) void node_state_k(const __hip_bfloat16* __restrict__ T,
                                                    const float* __restrict__ R,
                                                    const float* __restrict__ ps,
                                                    const float* __restrict__ W_state,
                                                    float* __restrict__ s_state, int step){
  __shared__ float sh[4];
  int n = blockIdx.x, h = threadIdx.x;
  int g = n / NPG;
  const float* instr = R + (size_t)g*(NSTEPS*HH) + step*HH;
  float ps0 = ps[g*4+0], ps1 = ps[g*4+1], ps2 = ps[g*4+2];
  const __hip_bfloat16* t = T + (size_t)n*(3*HH);
  float tv = ps0*__bfloat162float(t[h]) + ps1*__bfloat162float(t[HH+h]) + ps2*__bfloat162float(t[2*HH+h]);
  float v = eluf(instr[h]*tv) * W_state[h];
  float s = block_sum256(v, sh);
  if (h==0) s_state[n] = s;
}

__global__ __launch_bounds__(256) void seg_softmax_k(const float* __restrict__ x, float* __restrict__ y){
  __shared__ float sh[4];
  int b = blockIdx.x, i = threadIdx.x;
  float v = (i < NPG) ? x[b*NPG + i] : -1e30f;
  float m = block_max256(v, sh);
  float e = (i < NPG) ? expf(v - m) : 0.f;
  float s = block_sum256(e, sh);
  if (i < NPG) y[b*NPG + i] = e / s;
}

__global__ __launch_bounds__(256) void edge_scatter_k(const __hip_bfloat16* __restrict__ ET,
                                                      const float* __restrict__ R,
                                                      const float* __restrict__ dist,
                                                      const int* __restrict__ esrc,
                                                      const int* __restrict__ edst,
                                                      float* __restrict__ agg, int step){
  int e = blockIdx.x, h = threadIdx.x;
  int b = e / (NPG*DEG);
  const float* instr = R + (size_t)b*(NSTEPS*HH) + step*HH;
  float d = dist[esrc[e]];
  float v = eluf(instr[h] * __bfloat162float(ET[(size_t)e*HH + h])) * d;
  atomicAdd(&agg[(size_t)edst[e]*HH + h], v);
}

__global__ __launch_bounds__(256) void srel_k(const float* __restrict__ agg, const float* __restrict__ Wr,
                                              float* __restrict__ s_rel){
  __shared__ float sh[4];
  int n = blockIdx.x, h = threadIdx.x;
  float v = agg[(size_t)n*HH + h] * Wr[h];
  float s = block_sum256(v, sh);
  if (h==0) s_rel[n] = s;
}

__global__ void dist_update_k(const float* __restrict__ ps, const float* __restrict__ p_rel,
                              const float* __restrict__ p_state, float* __restrict__ dist){
  int n = blockIdx.x*256 + threadIdx.x;
  if (n >= NN) return;
  int g = n / NPG;
  float r = ps[g*4+3];
  dist[n] = r*p_rel[n] + (1.f-r)*p_state[n];
}

__global__ __launch_bounds__(256) void final_agg_k(const float* __restrict__ na, const float* __restrict__ dist,
                                                   const float* __restrict__ ps, float* __restrict__ aggregated){
  int b = blockIdx.x, h = threadIdx.x;
  float ps0 = ps[b*4+0], ps1 = ps[b*4+1], ps2 = ps[b*4+2];
  float acc = 0.f;
  for (int i=0;i<NPG;i++){
    int n = b*NPG + i;
    float d = dist[n];
    const float* a = na + (size_t)n*(3*HH);
    acc += d*(ps0*a[h] + ps1*a[HH+h] + ps2*a[2*HH+h]);
  }
  aggregated[b*HH + h] = acc;
}

__global__ void qa_build_k(const float* __restrict__ Q, const float* __restrict__ aggregated,
                           float* __restrict__ QA){
  int idx = blockIdx.x*256 + threadIdx.x;
  if (idx >= BB*2*HH) return;
  int b = idx >> 9, k = idx & 511;
  QA[idx] = (k < HH) ? Q[b*HH + k] : aggregated[b*HH + (k-HH)];
}

// ---------------- host ----------------
static inline void gemm_f32(hipStream_t s, const float* A, const float* B, float* C,
                            int M, int N, int K, int lda, int ldb, int ldc, const float* bias){
  dim3 g((N+63)/64, (M+63)/64);
  gemm_ab_k<<<g, 256, 0, s>>>(A,B,C,M,N,K,lda,ldb,ldc,bias);
}

extern "C" void kernel_launch(void* const* d_in, const int* in_sizes, int n_in,
                              void* d_out, int out_size, void* d_ws, size_t ws_size,
                              hipStream_t stream) {
  (void)in_sizes; (void)n_in; (void)out_size; (void)ws_size;
  const float* questions     = (const float*)d_in[0];
  const float* node_attrs    = (const float*)d_in[1];
  const float* edge_attrs    = (const float*)d_in[2];
  const float* vocab         = (const float*)d_in[3];
  const float* default_embed = (const float*)d_in[4];
  const float* W_norm        = (const float*)d_in[5];
  const float* lstm_Wih      = (const float*)d_in[6];
  const float* lstm_Whh      = (const float*)d_in[7];
  const float* lstm_bih      = (const float*)d_in[8];
  const float* lstm_bhh      = (const float*)d_in[9];
  const float* rnn_Wih       = (const float*)d_in[10];
  const float* rnn_Whh       = (const float*)d_in[11];
  const float* rnn_bih       = (const float*)d_in[12];
  const float* rnn_bhh       = (const float*)d_in[13];
  const float* prop_embeds   = (const float*)d_in[14];
  const float* Ws_property   = (const float*)d_in[15];
  const float* W_state       = (const float*)d_in[16];
  const float* W_relation    = (const float*)d_in[17];
  const float* lin_W         = (const float*)d_in[18];  // (2000, 512) row-major == Bt
  const float* lin_b         = (const float*)d_in[19];
  const int*   lengths       = (const int*)d_in[20];
  const int*   edge_src      = (const int*)d_in[23];
  const int*   edge_dst      = (const int*)d_in[24];
  float* out = (float*)d_out;

  char* base = (char*)d_ws;
  size_t off = 0;
  auto alloc = [&](size_t nbytes)->void*{
    void* p = base + off;
    off += (nbytes + 255) & ~(size_t)255;
    return p;
  };

  __hip_bfloat16* qbf    = (__hip_bfloat16*)alloc((size_t)BL*HH*2);
  __hip_bfloat16* WnT_bf = (__hip_bfloat16*)alloc((size_t)HH*HH*2);
  __hip_bfloat16* xw_bf  = (__hip_bfloat16*)alloc((size_t)BL*HH*2);
  __hip_bfloat16* Cbv    = (__hip_bfloat16*)alloc((size_t)VPAD*HH*2);
  __hip_bfloat16* vT_bf  = (__hip_bfloat16*)alloc((size_t)HH*KPAD*2);
  float* pm_def   = (float*)alloc((size_t)BL*4);
  float* Vtag     = (float*)alloc((size_t)BL*HH*4);
  float* WhhT     = (float*)alloc((size_t)HH*4*HH*4);
  float* bsum     = (float*)alloc((size_t)4*HH*4);
  float* rWihT    = (float*)alloc((size_t)HH*HH*4);
  float* rWhhT    = (float*)alloc((size_t)HH*HH*4);
  float* g2       = (float*)alloc((size_t)BB*4*HH*4);
  float* h_buf    = (float*)alloc((size_t)BB*HH*4);
  float* c_buf    = (float*)alloc((size_t)BB*HH*4);
  float* qproj    = (float*)alloc((size_t)BB*HH*4);
  float* hx       = (float*)alloc((size_t)BB*HH*4);
  float* Hins     = (float*)alloc((size_t)BB*NSTEPS*HH*4);
  float* R        = (float*)alloc((size_t)BB*NSTEPS*HH*4);
  float* prop_sim = (float*)alloc((size_t)BB*4*4);
  float* s_state  = (float*)alloc((size_t)NN*4);
  float* p_state  = (float*)alloc((size_t)NN*4);
  float* s_rel    = (float*)alloc((size_t)NN*4);
  float* p_rel    = (float*)alloc((size_t)NN*4);
  float* dist     = (float*)alloc((size_t)NN*4);
  float* aggregated = (float*)alloc((size_t)BB*HH*4);
  float* QA       = (float*)alloc((size_t)BB*2*HH*4);
  // union U: Pm_bf (4096 x 5024 bf16 = 41.2MB) then agg (38400 x 256 f32 = 39.3MB)
  char*  U        = (char*)alloc((size_t)BL*KPAD*2);
  __hip_bfloat16* Pm_bf = (__hip_bfloat16*)U;
  float* agg            = (float*)U;
  // Tf region (59MB bf16); gX (16.8MB f32) aliases its start (disjoint in time)
  char*  TfR      = (char*)alloc((size_t)NN*3*HH*2);
  __hip_bfloat16* Tf = (__hip_bfloat16*)TfR;
  float* gX          = (float*)TfR;
  // ET region (78.6MB bf16); logits chunk (21MB f32) aliases its start
  char*  ETR      = (char*)alloc((size_t)EE*HH*2);
  __hip_bfloat16* ET = (__hip_bfloat16*)ETR;
  float* logits      = (float*)ETR;

  // ---- setup ----
  init_k<<<256, 256, 0, stream>>>(h_buf, c_buf, hx, dist);
  cvt_bf16_k<<<(BL*HH/4+255)/256, 256, 0, stream>>>(questions, qbf, BL*HH);
  tr_cvt_k<<<(HH*HH+255)/256, 256, 0, stream>>>(W_norm, WnT_bf, HH, HH);
  build_cb_k<<<(VPAD*HH+255)/256, 256, 0, stream>>>(vocab, default_embed, Cbv);
  build_vt_k<<<(HH*KPAD+255)/256, 256, 0, stream>>>(vocab, vT_bf);
  transpose_k<<<(4*HH*HH+255)/256, 256, 0, stream>>>(lstm_Whh, WhhT, 4*HH, HH);
  transpose_k<<<(HH*HH+255)/256, 256, 0, stream>>>(rnn_Wih, rWihT, HH, HH);
  transpose_k<<<(HH*HH+255)/256, 256, 0, stream>>>(rnn_Whh, rWhhT, HH, HH);
  bsum_k<<<(4*HH+255)/256, 256, 0, stream>>>(lstm_bih, lstm_bhh, bsum);

  // ---- phase A: word embedding ----
  // xw = words @ W_norm   (bf16 out)
  mfma_bt_bf16_k<1><<<dim3(2,32,1), 256, 0, stream>>>(qbf, WnT_bf, nullptr, xw_bf,
      HH, HH, HH, HH, HH/32, HH/32, nullptr);
  for (int c=0; c<BL/CHUNK; c++){
    int r0 = c*CHUNK;
    // logits = xw @ Cb^T  (f32, ld VPAD)
    mfma_bt_bf16_k<0><<<dim3(VPAD/128, CHUNK/128, 1), 256, 0, stream>>>(
        xw_bf + (size_t)r0*HH, Cbv, logits, nullptr,
        HH, HH, VPAD, VPAD, HH/32, HH/32, nullptr);
    softmax_pm_k<<<CHUNK, 256, 0, stream>>>(logits, Pm_bf, pm_def, r0);
  }
  // Vtag = Pm @ vocab (split-K=8, atomic f32) + pm_def*words
  zero_k<<<(BL*HH+255)/256, 256, 0, stream>>>(Vtag, BL*HH);
  mfma_bt_bf16_k<2><<<dim3(HH/128, BL/128, 8), 256, 0, stream>>>(
      Pm_bf, vT_bf, Vtag, nullptr, KPAD, KPAD, HH, HH, KPAD/32, 20, nullptr);
  vtag_epi_k<<<BL, HH, 0, stream>>>(Vtag, pm_def, questions);

  // ---- phase B: LSTM encoder ----
  // gX = Vtag @ lstm_Wih^T + bsum  (f32-in MFMA; lstm_Wih is (1024,256) row-major = Bt)
  mfma_bt_f32_k<0><<<dim3(8,32,1), 256, 0, stream>>>(Vtag, lstm_Wih, gX, nullptr,
      HH, HH, 4*HH, 4*HH, HH/32, bsum);
  for (int t=0; t<LL; t++){
    gemm_f32(stream, h_buf, WhhT, g2, BB, 4*HH, HH, HH, 4*HH, 4*HH, nullptr);
    lstm_update_k<<<BB, HH, 0, stream>>>(gX, g2, h_buf, c_buf, lengths, t);
  }

  // ---- phase C: decoder RNN ----
  gemm_f32(stream, h_buf, rWihT, qproj, BB, HH, HH, HH, HH, HH, rnn_bih);
  for (int s=0; s<NSTEPS; s++){
    gemm_f32(stream, hx, rWhhT, g2, BB, HH, HH, HH, HH, HH, rnn_bhh);
    rnn_update_k<<<BB, HH, 0, stream>>>(qproj, g2, hx, Hins, s);
  }

  // ---- phase D: attention -> R ----
  attention_k<<<BB, 256, 0, stream>>>(Vtag, Hins, lengths, R);

  // ---- phase E: step-invariant heavy GEMMs (bf16 out). Clobbers gX/logits (dead). ----
  for (int p=0; p<3; p++)
    mfma_bt_f32_k<1><<<dim3(2,NN/128,1), 256, 0, stream>>>(
        node_attrs + (size_t)p*HH, Ws_property + (size_t)p*HH*HH,
        nullptr, Tf + (size_t)p*HH, 3*HH, HH, 3*HH, HH, HH/32, nullptr);
  mfma_bt_f32_k<1><<<dim3(2,EE/128,1), 256, 0, stream>>>(
      edge_attrs, Ws_property + (size_t)3*HH*HH,
      nullptr, ET, HH, HH, HH, HH, HH/32, nullptr);

  // ---- phase F: 4-step NSM loop (agg aliases Pm_bf, dead) ----
  for (int s=0; s<NSTEPS; s++){
    prop_sim_k<<<BB, 256, 0, stream>>>(R, prop_embeds, prop_sim, s);
    node_state_k<<<NN, 256, 0, stream>>>(Tf, R, prop_sim, W_state, s_state, s);
    seg_softmax_k<<<BB, 256, 0, stream>>>(s_state, p_state);
    zero_k<<<(NN*HH+255)/256, 256, 0, stream>>>(agg, NN*HH);
    edge_scatter_k<<<EE, 256, 0, stream>>>(ET, R, dist, edge_src, edge_dst, agg, s);
    srel_k<<<NN, 256, 0, stream>>>(agg, W_relation, s_rel);
    seg_softmax_k<<<BB, 256, 0, stream>>>(s_rel, p_rel);
    dist_update_k<<<(NN+255)/256, 256, 0, stream>>>(prop_sim, p_rel, p_state, dist);
  }

  // ---- phase G: readout ----
  final_agg_k<<<BB, 256, 0, stream>>>(node_attrs, dist, prop_sim, aggregated);
  qa_build_k<<<(BB*2*HH+255)/256, 256, 0, stream>>>(h_buf, aggregated, QA);
  // out = QA @ lin_W^T + lin_b   (lin_W (2000,512) row-major = Bt; N padded to 2048)
  mfma_bt_f32_k<0><<<dim3(16,2,1), 256, 0, stream>>>(QA, lin_W, out, nullptr,
      2*HH, 2*HH, OUTD, OUTD, 2*HH/32, lin_b);
}

// Round 3
// 1446.605 us; speedup vs baseline: 4.3426x; 1.6146x over previous
//
#include <hip/hip_runtime.h>
#include <hip/hip_bf16.h>
#include <math.h>

// Problem constants
#define BB 256
#define LL 16
#define HH 256
#define VV 5000
#define NPG 150
#define DEG 4
#define NSTEPS 4
#define OUTD 2000
#define NN (BB*NPG)      // 38400
#define EE (BB*NPG*DEG)  // 153600
#define BL (BB*LL)       // 4096
#define CHUNK 1024       // phase-A row chunk
#define VPAD 5120        // logits column pad (40*128)
#define KPAD 5024        // Pm K pad (157*32)

// ---------------- helpers ----------------
__device__ __forceinline__ float wred_sum(float v){
  #pragma unroll
  for(int o=32;o;o>>=1) v += __shfl_down(v,o,64);
  return v;
}
__device__ __forceinline__ float wred_max(float v){
  #pragma unroll
  for(int o=32;o;o>>=1) v = fmaxf(v,__shfl_down(v,o,64));
  return v;
}
__device__ __forceinline__ float block_sum256(float v, float* sh){
  v = wred_sum(v);
  __syncthreads();
  if((threadIdx.x&63)==0) sh[threadIdx.x>>6]=v;
  __syncthreads();
  return sh[0]+sh[1]+sh[2]+sh[3];
}
__device__ __forceinline__ float block_max256(float v, float* sh){
  v = wred_max(v);
  __syncthreads();
  if((threadIdx.x&63)==0) sh[threadIdx.x>>6]=v;
  __syncthreads();
  return fmaxf(fmaxf(sh[0],sh[1]),fmaxf(sh[2],sh[3]));
}
__device__ __forceinline__ float eluf(float x){ return x>0.f ? x : expm1f(x); }
__device__ __forceinline__ float sigf(float x){ return 1.f/(1.f+expf(-x)); }
__device__ __forceinline__ float b2f(unsigned short s){
  union{float f; unsigned int u;} x; x.u = ((unsigned int)s)<<16; return x.f;
}

// async global->LDS 16B (gfx950), lds dest = wave-uniform base + lane*16
__device__ __forceinline__ void async16(void* lds, const void* g){
  __builtin_amdgcn_global_load_lds(
      (const __attribute__((address_space(1))) unsigned int*)g,
      (__attribute__((address_space(3))) unsigned int*)lds, 16, 0, 0);
}

typedef __attribute__((ext_vector_type(8))) short short8;
typedef __attribute__((ext_vector_type(4))) float f32x4;

// =======================================================================
// MFMA GEMM, C[m,n] = sum_k A[m,k]*Bt[n,k].  128x128 tile, BK=32, 4 waves.
// EPI: 0 = f32 store (+bias, col<Nreal), 1 = bf16 store, 2 = f32 atomicAdd
// =======================================================================
template<int EPI>
__global__ __launch_bounds__(256) void mfma_bt_bf16_k(
    const __hip_bfloat16* __restrict__ A, const __hip_bfloat16* __restrict__ Bt,
    float* __restrict__ Cf, __hip_bfloat16* __restrict__ Cb,
    int lda, int ldb, int ldc, int Nreal,
    int kItersTotal, int kPerSplit, const float* __restrict__ bias)
{
  __shared__ __hip_bfloat16 As[128*32];
  __shared__ __hip_bfloat16 Bs[128*32];
  const int bm = blockIdx.y*128, bn = blockIdx.x*128;
  const int tid = threadIdx.x;
  int k0 = blockIdx.z * kPerSplit;
  int k1 = k0 + kPerSplit; if (k1 > kItersTotal) k1 = kItersTotal;
  const int lane = tid & 63, wave = tid >> 6;
  const int quad = lane >> 4, r16 = lane & 15;
  const int wr = wave >> 1, wc = wave & 1;
  f32x4 acc[4][4] = {};
  const int c0 = tid, c1 = tid + 256;
  const int ar0 = c0 >> 2, ak0 = (c0 & 3)*8;
  const int ar1 = c1 >> 2, ak1 = (c1 & 3)*8;
  const __hip_bfloat16* Ab = A + (size_t)bm*lda;
  const __hip_bfloat16* Bb = Bt + (size_t)bn*ldb;
  for (int kk = k0; kk < k1; ++kk){
    const int kb = kk*32;
    async16(&As[c0*8], Ab + (size_t)ar0*lda + kb + ak0);
    async16(&As[c1*8], Ab + (size_t)ar1*lda + kb + ak1);
    async16(&Bs[c0*8], Bb + (size_t)ar0*ldb + kb + ak0);
    async16(&Bs[c1*8], Bb + (size_t)ar1*ldb + kb + ak1);
    __syncthreads();
    short8 av[4], bv[4];
    #pragma unroll
    for (int i=0;i<4;i++){
      av[i] = *(const short8*)&As[(wr*64 + i*16 + r16)*32 + quad*8];
      bv[i] = *(const short8*)&Bs[(wc*64 + i*16 + r16)*32 + quad*8];
    }
    #pragma unroll
    for (int i=0;i<4;i++)
      #pragma unroll
      for (int j=0;j<4;j++)
        acc[i][j] = __builtin_amdgcn_mfma_f32_16x16x32_bf16(av[i], bv[j], acc[i][j], 0,0,0);
    __syncthreads();
  }
  #pragma unroll
  for (int i=0;i<4;i++){
    int row = bm + wr*64 + i*16 + quad*4;
    #pragma unroll
    for (int j=0;j<4;j++){
      int col = bn + wc*64 + j*16 + r16;
      if (col >= Nreal) continue;
      #pragma unroll
      for (int r=0;r<4;r++){
        float v = acc[i][j][r];
        if (EPI==0){ if (bias) v += bias[col]; Cf[(size_t)(row+r)*ldc + col] = v; }
        else if (EPI==1){ Cb[(size_t)(row+r)*ldc + col] = __float2bfloat16(v); }
        else { atomicAdd(&Cf[(size_t)(row+r)*ldc + col], v); }
      }
    }
  }
}

// Same GEMM but f32 global operands, converted to bf16 during VALU staging.
template<int EPI>
__global__ __launch_bounds__(256) void mfma_bt_f32_k(
    const float* __restrict__ A, const float* __restrict__ Bt,
    float* __restrict__ Cf, __hip_bfloat16* __restrict__ Cb,
    int lda, int ldb, int ldc, int Nreal,
    int kIters, const float* __restrict__ bias)
{
  __shared__ __hip_bfloat16 As[128*32];
  __shared__ __hip_bfloat16 Bs[128*32];
  const int bm = blockIdx.y*128, bn = blockIdx.x*128;
  const int tid = threadIdx.x;
  const int lane = tid & 63, wave = tid >> 6;
  const int quad = lane >> 4, r16 = lane & 15;
  const int wr = wave >> 1, wc = wave & 1;
  f32x4 acc[4][4] = {};
  for (int kk = 0; kk < kIters; ++kk){
    const int kb = kk*32;
    #pragma unroll
    for (int i=0;i<4;i++){
      int c = tid + i*256;
      int row = c >> 3, kc = (c & 7)*4;
      float4 v = *(const float4*)(A + (size_t)(bm+row)*lda + kb + kc);
      As[row*32+kc]   = __float2bfloat16(v.x);
      As[row*32+kc+1] = __float2bfloat16(v.y);
      As[row*32+kc+2] = __float2bfloat16(v.z);
      As[row*32+kc+3] = __float2bfloat16(v.w);
    }
    #pragma unroll
    for (int i=0;i<4;i++){
      int c = tid + i*256;
      int row = c >> 3, kc = (c & 7)*4;
      float4 v = {0.f,0.f,0.f,0.f};
      if (bn + row < Nreal) v = *(const float4*)(Bt + (size_t)(bn+row)*ldb + kb + kc);
      Bs[row*32+kc]   = __float2bfloat16(v.x);
      Bs[row*32+kc+1] = __float2bfloat16(v.y);
      Bs[row*32+kc+2] = __float2bfloat16(v.z);
      Bs[row*32+kc+3] = __float2bfloat16(v.w);
    }
    __syncthreads();
    short8 av[4], bv[4];
    #pragma unroll
    for (int i=0;i<4;i++){
      av[i] = *(const short8*)&As[(wr*64 + i*16 + r16)*32 + quad*8];
      bv[i] = *(const short8*)&Bs[(wc*64 + i*16 + r16)*32 + quad*8];
    }
    #pragma unroll
    for (int i=0;i<4;i++)
      #pragma unroll
      for (int j=0;j<4;j++)
        acc[i][j] = __builtin_amdgcn_mfma_f32_16x16x32_bf16(av[i], bv[j], acc[i][j], 0,0,0);
    __syncthreads();
  }
  #pragma unroll
  for (int i=0;i<4;i++){
    int row = bm + wr*64 + i*16 + quad*4;
    #pragma unroll
    for (int j=0;j<4;j++){
      int col = bn + wc*64 + j*16 + r16;
      if (col >= Nreal) continue;
      #pragma unroll
      for (int r=0;r<4;r++){
        float v = acc[i][j][r];
        if (EPI==0){ if (bias) v += bias[col]; Cf[(size_t)(row+r)*ldc + col] = v; }
        else { Cb[(size_t)(row+r)*ldc + col] = __float2bfloat16(v); }
      }
    }
  }
}

// ---------------- fp32 SIMD GEMM (small decoder steps) ----------------
__global__ __launch_bounds__(256) void gemm_ab_k(
    const float* __restrict__ A, const float* __restrict__ B, float* __restrict__ C,
    int M, int N, int K, int lda, int ldb, int ldc,
    const float* __restrict__ bias)
{
  __shared__ __align__(16) float Asf[16][68];
  __shared__ __align__(16) float Bsf[16][64];
  const int bm = blockIdx.y*64, bn = blockIdx.x*64;
  const int tid = threadIdx.x;
  const int tx = tid & 15, ty = tid >> 4;
  float acc[4][4] = {};
  for (int k0 = 0; k0 < K; k0 += 16) {
    #pragma unroll
    for (int i=0;i<4;i++){
      int idx = tid + i*256;
      int r = idx >> 4, cc = idx & 15;
      int gm = bm + r, gk = k0 + cc;
      Asf[cc][r] = (gm < M && gk < K) ? A[(size_t)gm*lda + gk] : 0.f;
    }
    #pragma unroll
    for (int i=0;i<4;i++){
      int idx = tid + i*256;
      int r = idx >> 6, cc = idx & 63;
      int gk = k0 + r, gn = bn + cc;
      Bsf[r][cc] = (gk < K && gn < N) ? B[(size_t)gk*ldb + gn] : 0.f;
    }
    __syncthreads();
    #pragma unroll
    for (int k=0;k<16;k++){
      float4 avv = *reinterpret_cast<const float4*>(&Asf[k][ty*4]);
      float4 bvv = *reinterpret_cast<const float4*>(&Bsf[k][tx*4]);
      float a[4]={avv.x,avv.y,avv.z,avv.w};
      float b[4]={bvv.x,bvv.y,bvv.z,bvv.w};
      #pragma unroll
      for(int i=0;i<4;i++)
        #pragma unroll
        for(int j=0;j<4;j++)
          acc[i][j] = fmaf(a[i], b[j], acc[i][j]);
    }
    __syncthreads();
  }
  #pragma unroll
  for(int i=0;i<4;i++){
    int gm = bm + ty*4 + i;
    if (gm >= M) continue;
    #pragma unroll
    for(int j=0;j<4;j++){
      int gn = bn + tx*4 + j;
      if (gn >= N) continue;
      float v = acc[i][j];
      if (bias) v += bias[gn];
      C[(size_t)gm*ldc + gn] = v;
    }
  }
}

// ---------------- small utility kernels ----------------
__global__ void transpose_k(const float* __restrict__ src, float* __restrict__ dst, int R, int Ccols){
  int idx = blockIdx.x*256 + threadIdx.x;
  if (idx >= R*Ccols) return;
  int r = idx / Ccols, c = idx % Ccols;
  dst[(size_t)c*R + r] = src[idx];
}

__global__ void cvt_bf16_k(const float* __restrict__ src, __hip_bfloat16* __restrict__ dst, int n){
  int i = (blockIdx.x*256 + threadIdx.x)*4;
  if (i >= n) return;
  float4 v = *(const float4*)(src + i);
  dst[i]   = __float2bfloat16(v.x);
  dst[i+1] = __float2bfloat16(v.y);
  dst[i+2] = __float2bfloat16(v.z);
  dst[i+3] = __float2bfloat16(v.w);
}

__global__ void tr_cvt_k(const float* __restrict__ src, __hip_bfloat16* __restrict__ dst, int R, int Ccols){
  int idx = blockIdx.x*256 + threadIdx.x;
  if (idx >= R*Ccols) return;
  int r = idx / Ccols, c = idx % Ccols;
  dst[(size_t)c*R + r] = __float2bfloat16(src[idx]);
}

__global__ void build_cb_k(const float* __restrict__ vocab, const float* __restrict__ de,
                           __hip_bfloat16* __restrict__ Cb){
  int idx = blockIdx.x*256 + threadIdx.x;
  if (idx >= VPAD*HH) return;
  int v = idx >> 8, h = idx & 255;
  float x = (v < VV) ? vocab[(size_t)v*HH + h] : (v == VV ? de[h] : 0.f);
  Cb[idx] = __float2bfloat16(x);
}

__global__ void build_vt_k(const float* __restrict__ vocab, __hip_bfloat16* __restrict__ VT){
  int idx = blockIdx.x*256 + threadIdx.x;
  if (idx >= HH*KPAD) return;
  int h = idx / KPAD, v = idx % KPAD;
  VT[idx] = __float2bfloat16(v < VV ? vocab[(size_t)v*HH + h] : 0.f);
}

__global__ void bsum_k(const float* a, const float* b, float* o){
  int i = blockIdx.x*256 + threadIdx.x;
  if (i < 4*HH) o[i] = a[i] + b[i];
}

__global__ void init_k(float* h, float* c, __hip_bfloat16* h_bf, float* hx, float* dist, float* s_rel){
  int idx = blockIdx.x*256 + threadIdx.x;
  if (idx < BB*HH){ h[idx]=0.f; c[idx]=0.f; hx[idx]=0.f; h_bf[idx]=__float2bfloat16(0.f); }
  if (idx < NN){ dist[idx] = 1.f/150.f; s_rel[idx] = 0.f; }
}

__global__ void zero_k(float* p, int n){
  int idx = blockIdx.x*256 + threadIdx.x;
  if (idx < n) p[idx] = 0.f;
}

// softmax over 5001 valid logits (ld VPAD) -> bf16 Pm row (ld KPAD) + pm_def
__global__ __launch_bounds__(256) void softmax_pm_k(const float* __restrict__ logits,
                                                    __hip_bfloat16* __restrict__ Pm,
                                                    float* __restrict__ pm_def, int r0){
  __shared__ float sh[4];
  int r = blockIdx.x;
  const float* row = logits + (size_t)r*VPAD;
  float mx = -1e30f;
  for (int i=threadIdx.x; i<VV+1; i+=256) mx = fmaxf(mx, row[i]);
  mx = block_max256(mx, sh);
  float s = 0.f;
  for (int i=threadIdx.x; i<VV+1; i+=256) s += expf(row[i]-mx);
  s = block_sum256(s, sh);
  float inv = 1.f/s;
  __hip_bfloat16* prow = Pm + (size_t)(r0+r)*KPAD;
  for (int i=threadIdx.x; i<KPAD; i+=256){
    float p = (i < VV) ? expf(row[i]-mx)*inv : 0.f;
    prow[i] = __float2bfloat16(p);
  }
  if (threadIdx.x==0) pm_def[r0+r] = expf(row[VV]-mx)*inv;
}

__global__ void vtag_epi_k(float* __restrict__ Vtag, const float* __restrict__ pm_def,
                           const float* __restrict__ words){
  int r = blockIdx.x, h = threadIdx.x;
  size_t o = (size_t)r*HH + h;
  Vtag[o] += pm_def[r] * words[o];
}

// LSTM cell update; maintains bf16 mirror of h for the MFMA recurrent GEMM
__global__ void lstm_update_k(const float* __restrict__ gX, const float* __restrict__ g2,
                              float* __restrict__ h, float* __restrict__ c,
                              __hip_bfloat16* __restrict__ h_bf,
                              const int* __restrict__ lengths, int t){
  int b = blockIdx.x, hh = threadIdx.x;
  int idx = b*HH + hh;
  const float* gx = gX + (size_t)(b*LL + t)*(4*HH);
  const float* gg = g2 + (size_t)b*(4*HH);
  float gi = gx[hh]        + gg[hh];
  float gf = gx[HH+hh]     + gg[HH+hh];
  float gc = gx[2*HH+hh]   + gg[2*HH+hh];
  float go = gx[3*HH+hh]   + gg[3*HH+hh];
  float cn = sigf(gf)*c[idx] + sigf(gi)*tanhf(gc);
  float hn = sigf(go)*tanhf(cn);
  bool upd = (t < lengths[b]);
  float hf = upd ? hn : h[idx];
  float cf = upd ? cn : c[idx];
  h[idx] = hf; c[idx] = cf;
  h_bf[idx] = __float2bfloat16(hf);
}

__global__ void rnn_update_k(const float* __restrict__ qproj, const float* __restrict__ g2,
                             float* __restrict__ hx, float* __restrict__ Hins, int s){
  int b = blockIdx.x, hh = threadIdx.x;
  int idx = b*HH + hh;
  float v = fmaxf(qproj[idx] + g2[idx], 0.f);
  hx[idx] = v;
  Hins[(size_t)b*(NSTEPS*HH) + s*HH + hh] = v;
}

// attention per graph
__global__ __launch_bounds__(256) void attention_k(const float* __restrict__ Vtag,
                                                   const float* __restrict__ Hins,
                                                   const int* __restrict__ lengths,
                                                   float* __restrict__ R){
  __shared__ float Vl[LL][HH];
  __shared__ float Hn[NSTEPS][HH];
  __shared__ float att[NSTEPS][LL];
  int b = blockIdx.x, tid = threadIdx.x;
  for (int idx=tid; idx<LL*HH; idx+=256){ int l=idx>>8, h=idx&255; Vl[l][h] = Vtag[((size_t)b*LL+l)*HH + h]; }
  for (int idx=tid; idx<NSTEPS*HH; idx+=256){ Hn[idx>>8][idx&255] = Hins[(size_t)b*(NSTEPS*HH) + idx]; }
  __syncthreads();
  if (tid < NSTEPS*LL){
    int n2 = tid>>4, l = tid&15;
    float s = 0.f;
    for (int k=0;k<HH;k++) s += Hn[n2][k]*Vl[l][k];
    att[n2][l] = s;
  }
  __syncthreads();
  int len = lengths[b];
  if (tid < NSTEPS){
    float m = -1e30f;
    for (int l=0;l<len;l++) m = fmaxf(m, att[tid][l]);
    float s = 0.f;
    for (int l=0;l<LL;l++){ float e = (l<len)? expf(att[tid][l]-m) : 0.f; att[tid][l]=e; s+=e; }
    float inv = 1.f/s;
    for (int l=0;l<LL;l++) att[tid][l] *= inv;
  }
  __syncthreads();
  {
    int n2 = tid>>6, h0 = (tid&63)*4;
    float r0=0,r1=0,r2=0,r3=0;
    for (int l=0;l<LL;l++){
      float w = att[n2][l];
      r0 += w*Vl[l][h0]; r1 += w*Vl[l][h0+1]; r2 += w*Vl[l][h0+2]; r3 += w*Vl[l][h0+3];
    }
    float* o = R + (size_t)b*(NSTEPS*HH) + n2*HH + h0;
    o[0]=r0; o[1]=r1; o[2]=r2; o[3]=r3;
  }
}

// prop_sim for ALL steps (depends only on R): psa[s][b][4]
__global__ __launch_bounds__(256) void prop_sim_all_k(const float* __restrict__ R,
                                                      const float* __restrict__ pe,
                                                      float* __restrict__ psa){
  __shared__ float sp[4];
  int gb = blockIdx.x;              // gb = s*BB + b
  int s = gb >> 8, b = gb & 255;
  int tid = threadIdx.x;
  int p = tid>>6, lane = tid&63;
  const float* instr = R + (size_t)b*(NSTEPS*HH) + s*HH;
  float v = 0.f;
  for (int h=lane; h<HH; h+=64) v += instr[h]*pe[p*HH+h];
  v = wred_sum(v);
  if (lane==0) sp[p] = v;
  __syncthreads();
  if (tid==0){
    float m = fmaxf(fmaxf(sp[0],sp[1]),fmaxf(sp[2],sp[3]));
    float e0=expf(sp[0]-m), e1=expf(sp[1]-m), e2=expf(sp[2]-m), e3=expf(sp[3]-m);
    float ss = e0+e1+e2+e3;
    float* o = psa + (size_t)s*BB*4 + b*4;
    o[0]=e0/ss; o[1]=e1/ss; o[2]=e2/ss; o[3]=e3/ss;
  }
}

// K1: node s_state (wave per node) + edge w[e]-scalar scatter into s_rel (wave per edge)
__global__ __launch_bounds__(256) void nsm_scores_k(
    const __hip_bfloat16* __restrict__ Tf, const __hip_bfloat16* __restrict__ ET,
    const float* __restrict__ R, const float* __restrict__ psa_s,
    const float* __restrict__ W_state, const float* __restrict__ Wr,
    const float* __restrict__ dist, const int* __restrict__ esrc, const int* __restrict__ edst,
    float* __restrict__ s_state, float* __restrict__ s_rel, int step)
{
  const int wave = threadIdx.x >> 6, lane = threadIdx.x & 63;
  const int h0 = lane*4;
  if (blockIdx.x < NN/4){
    int n = blockIdx.x*4 + wave;
    int g = n / NPG;
    const float* instr = R + (size_t)g*(NSTEPS*HH) + step*HH;
    float ps0 = psa_s[g*4], ps1 = psa_s[g*4+1], ps2 = psa_s[g*4+2];
    const unsigned short* t = (const unsigned short*)(Tf + (size_t)n*(3*HH));
    ushort4 t0 = *(const ushort4*)(t + h0);
    ushort4 t1 = *(const ushort4*)(t + HH + h0);
    ushort4 t2 = *(const ushort4*)(t + 2*HH + h0);
    float4 iv = *(const float4*)(instr + h0);
    float4 wv = *(const float4*)(W_state + h0);
    float acc;
    acc  = eluf(iv.x*(ps0*b2f(t0.x)+ps1*b2f(t1.x)+ps2*b2f(t2.x)))*wv.x;
    acc += eluf(iv.y*(ps0*b2f(t0.y)+ps1*b2f(t1.y)+ps2*b2f(t2.y)))*wv.y;
    acc += eluf(iv.z*(ps0*b2f(t0.z)+ps1*b2f(t1.z)+ps2*b2f(t2.z)))*wv.z;
    acc += eluf(iv.w*(ps0*b2f(t0.w)+ps1*b2f(t1.w)+ps2*b2f(t2.w)))*wv.w;
    acc = wred_sum(acc);
    if (lane==0) s_state[n] = acc;
  } else {
    int e = (blockIdx.x - NN/4)*4 + wave;
    int b = e / (NPG*DEG);
    const float* instr = R + (size_t)b*(NSTEPS*HH) + step*HH;
    const unsigned short* et = (const unsigned short*)(ET + (size_t)e*HH);
    ushort4 ev = *(const ushort4*)(et + h0);
    float4 iv = *(const float4*)(instr + h0);
    float4 wv = *(const float4*)(Wr + h0);
    float acc;
    acc  = eluf(iv.x*b2f(ev.x))*wv.x;
    acc += eluf(iv.y*b2f(ev.y))*wv.y;
    acc += eluf(iv.z*b2f(ev.z))*wv.z;
    acc += eluf(iv.w*b2f(ev.w))*wv.w;
    acc = wred_sum(acc);
    if (lane==0) atomicAdd(&s_rel[edst[e]], dist[esrc[e]]*acc);
  }
}

// K2: per-graph — both segment softmaxes + dist update; zeroes s_rel for next step
__global__ __launch_bounds__(256) void nsm_update_k(
    const float* __restrict__ s_state, float* __restrict__ s_rel,
    const float* __restrict__ psa_s, float* __restrict__ dist)
{
  __shared__ float sh[4];
  int b = blockIdx.x, i = threadIdx.x;
  bool ok = (i < NPG);
  float ss = ok ? s_state[b*NPG + i] : -1e30f;
  float sr = ok ? s_rel[b*NPG + i]   : -1e30f;
  float m1 = block_max256(ss, sh);
  float e1 = ok ? expf(ss - m1) : 0.f;
  float d1 = block_sum256(e1, sh);
  float m2 = block_max256(sr, sh);
  float e2 = ok ? expf(sr - m2) : 0.f;
  float d2 = block_sum256(e2, sh);
  if (ok){
    float pst = e1/d1, prl = e2/d2;
    float r = psa_s[b*4+3];
    dist[b*NPG + i] = r*prl + (1.f-r)*pst;
    s_rel[b*NPG + i] = 0.f;
  }
}

__global__ __launch_bounds__(256) void final_agg_k(const float* __restrict__ na, const float* __restrict__ dist,
                                                   const float* __restrict__ ps, float* __restrict__ aggregated){
  int b = blockIdx.x, h = threadIdx.x;
  float ps0 = ps[b*4+0], ps1 = ps[b*4+1], ps2 = ps[b*4+2];
  float acc = 0.f;
  for (int i=0;i<NPG;i++){
    int n = b*NPG + i;
    float d = dist[n];
    const float* a = na + (size_t)n*(3*HH);
    acc += d*(ps0*a[h] + ps1*a[HH+h] + ps2*a[2*HH+h]);
  }
  aggregated[b*HH + h] = acc;
}

__global__ void qa_build_k(const float* __restrict__ Q, const float* __restrict__ aggregated,
                           float* __restrict__ QA){
  int idx = blockIdx.x*256 + threadIdx.x;
  if (idx >= BB*2*HH) return;
  int b = idx >> 9, k = idx & 511;
  QA[idx] = (k < HH) ? Q[b*HH + k] : aggregated[b*HH + (k-HH)];
}

// ---------------- host ----------------
static inline void gemm_f32(hipStream_t s, const float* A, const float* B, float* C,
                            int M, int N, int K, int lda, int ldb, int ldc, const float* bias){
  dim3 g((N+63)/64, (M+63)/64);
  gemm_ab_k<<<g, 256, 0, s>>>(A,B,C,M,N,K,lda,ldb,ldc,bias);
}

extern "C" void kernel_launch(void* const* d_in, const int* in_sizes, int n_in,
                              void* d_out, int out_size, void* d_ws, size_t ws_size,
                              hipStream_t stream) {
  (void)in_sizes; (void)n_in; (void)out_size; (void)ws_size;
  const float* questions     = (const float*)d_in[0];
  const float* node_attrs    = (const float*)d_in[1];
  const float* edge_attrs    = (const float*)d_in[2];
  const float* vocab         = (const float*)d_in[3];
  const float* default_embed = (const float*)d_in[4];
  const float* W_norm        = (const float*)d_in[5];
  const float* lstm_Wih      = (const float*)d_in[6];
  const float* lstm_Whh      = (const float*)d_in[7];  // (1024,256) row-major == Bt
  const float* lstm_bih      = (const float*)d_in[8];
  const float* lstm_bhh      = (const float*)d_in[9];
  const float* rnn_Wih       = (const float*)d_in[10];
  const float* rnn_Whh       = (const float*)d_in[11];
  const float* rnn_bih       = (const float*)d_in[12];
  const float* rnn_bhh       = (const float*)d_in[13];
  const float* prop_embeds   = (const float*)d_in[14];
  const float* Ws_property   = (const float*)d_in[15];
  const float* W_state       = (const float*)d_in[16];
  const float* W_relation    = (const float*)d_in[17];
  const float* lin_W         = (const float*)d_in[18];  // (2000,512) row-major == Bt
  const float* lin_b         = (const float*)d_in[19];
  const int*   lengths       = (const int*)d_in[20];
  const int*   edge_src      = (const int*)d_in[23];
  const int*   edge_dst      = (const int*)d_in[24];
  float* out = (float*)d_out;

  char* base = (char*)d_ws;
  size_t off = 0;
  auto alloc = [&](size_t nbytes)->void*{
    void* p = base + off;
    off += (nbytes + 255) & ~(size_t)255;
    return p;
  };

  __hip_bfloat16* qbf    = (__hip_bfloat16*)alloc((size_t)BL*HH*2);
  __hip_bfloat16* WnT_bf = (__hip_bfloat16*)alloc((size_t)HH*HH*2);
  __hip_bfloat16* xw_bf  = (__hip_bfloat16*)alloc((size_t)BL*HH*2);
  __hip_bfloat16* Cbv    = (__hip_bfloat16*)alloc((size_t)VPAD*HH*2);
  __hip_bfloat16* vT_bf  = (__hip_bfloat16*)alloc((size_t)HH*KPAD*2);
  __hip_bfloat16* Whh_bf = (__hip_bfloat16*)alloc((size_t)4*HH*HH*2);
  __hip_bfloat16* h_bf   = (__hip_bfloat16*)alloc((size_t)BB*HH*2);
  float* pm_def   = (float*)alloc((size_t)BL*4);
  float* Vtag     = (float*)alloc((size_t)BL*HH*4);
  float* bsum     = (float*)alloc((size_t)4*HH*4);
  float* rWihT    = (float*)alloc((size_t)HH*HH*4);
  float* rWhhT    = (float*)alloc((size_t)HH*HH*4);
  float* g2       = (float*)alloc((size_t)BB*4*HH*4);
  float* h_buf    = (float*)alloc((size_t)BB*HH*4);
  float* c_buf    = (float*)alloc((size_t)BB*HH*4);
  float* qproj    = (float*)alloc((size_t)BB*HH*4);
  float* hx       = (float*)alloc((size_t)BB*HH*4);
  float* Hins     = (float*)alloc((size_t)BB*NSTEPS*HH*4);
  float* R        = (float*)alloc((size_t)BB*NSTEPS*HH*4);
  float* psa      = (float*)alloc((size_t)NSTEPS*BB*4*4);
  float* s_state  = (float*)alloc((size_t)NN*4);
  float* s_rel    = (float*)alloc((size_t)NN*4);
  float* dist     = (float*)alloc((size_t)NN*4);
  float* aggregated = (float*)alloc((size_t)BB*HH*4);
  float* QA       = (float*)alloc((size_t)BB*2*HH*4);
  // Pm_bf (4096 x 5024 bf16 = 41.2MB)
  __hip_bfloat16* Pm_bf = (__hip_bfloat16*)alloc((size_t)BL*KPAD*2);
  // Tf region (59MB bf16); gX (16.8MB f32) aliases its start (disjoint in time)
  char*  TfR      = (char*)alloc((size_t)NN*3*HH*2);
  __hip_bfloat16* Tf = (__hip_bfloat16*)TfR;
  float* gX          = (float*)TfR;
  // ET region (78.6MB bf16); logits chunk (21MB f32) aliases its start
  char*  ETR      = (char*)alloc((size_t)EE*HH*2);
  __hip_bfloat16* ET = (__hip_bfloat16*)ETR;
  float* logits      = (float*)ETR;

  // ---- setup ----
  init_k<<<256, 256, 0, stream>>>(h_buf, c_buf, h_bf, hx, dist, s_rel);
  cvt_bf16_k<<<(BL*HH/4+255)/256, 256, 0, stream>>>(questions, qbf, BL*HH);
  tr_cvt_k<<<(HH*HH+255)/256, 256, 0, stream>>>(W_norm, WnT_bf, HH, HH);
  build_cb_k<<<(VPAD*HH+255)/256, 256, 0, stream>>>(vocab, default_embed, Cbv);
  build_vt_k<<<(HH*KPAD+255)/256, 256, 0, stream>>>(vocab, vT_bf);
  cvt_bf16_k<<<(4*HH*HH/4+255)/256, 256, 0, stream>>>(lstm_Whh, Whh_bf, 4*HH*HH);
  transpose_k<<<(HH*HH+255)/256, 256, 0, stream>>>(rnn_Wih, rWihT, HH, HH);
  transpose_k<<<(HH*HH+255)/256, 256, 0, stream>>>(rnn_Whh, rWhhT, HH, HH);
  bsum_k<<<(4*HH+255)/256, 256, 0, stream>>>(lstm_bih, lstm_bhh, bsum);

  // ---- phase A: word embedding ----
  mfma_bt_bf16_k<1><<<dim3(2,32,1), 256, 0, stream>>>(qbf, WnT_bf, nullptr, xw_bf,
      HH, HH, HH, HH, HH/32, HH/32, nullptr);
  for (int c=0; c<BL/CHUNK; c++){
    int r0 = c*CHUNK;
    mfma_bt_bf16_k<0><<<dim3(VPAD/128, CHUNK/128, 1), 256, 0, stream>>>(
        xw_bf + (size_t)r0*HH, Cbv, logits, nullptr,
        HH, HH, VPAD, VPAD, HH/32, HH/32, nullptr);
    softmax_pm_k<<<CHUNK, 256, 0, stream>>>(logits, Pm_bf, pm_def, r0);
  }
  zero_k<<<(BL*HH+255)/256, 256, 0, stream>>>(Vtag, BL*HH);
  mfma_bt_bf16_k<2><<<dim3(HH/128, BL/128, 8), 256, 0, stream>>>(
      Pm_bf, vT_bf, Vtag, nullptr, KPAD, KPAD, HH, HH, KPAD/32, 20, nullptr);
  vtag_epi_k<<<BL, HH, 0, stream>>>(Vtag, pm_def, questions);

  // ---- phase B: LSTM encoder ----
  mfma_bt_f32_k<0><<<dim3(8,32,1), 256, 0, stream>>>(Vtag, lstm_Wih, gX, nullptr,
      HH, HH, 4*HH, 4*HH, HH/32, bsum);
  for (int t=0; t<LL; t++){
    mfma_bt_bf16_k<0><<<dim3(8,2,1), 256, 0, stream>>>(h_bf, Whh_bf, g2, nullptr,
        HH, HH, 4*HH, 4*HH, HH/32, HH/32, nullptr);
    lstm_update_k<<<BB, HH, 0, stream>>>(gX, g2, h_buf, c_buf, h_bf, lengths, t);
  }

  // ---- phase C: decoder RNN ----
  gemm_f32(stream, h_buf, rWihT, qproj, BB, HH, HH, HH, HH, HH, rnn_bih);
  for (int s=0; s<NSTEPS; s++){
    gemm_f32(stream, hx, rWhhT, g2, BB, HH, HH, HH, HH, HH, rnn_bhh);
    rnn_update_k<<<BB, HH, 0, stream>>>(qproj, g2, hx, Hins, s);
  }

  // ---- phase D: attention -> R; prop_sim for all steps ----
  attention_k<<<BB, 256, 0, stream>>>(Vtag, Hins, lengths, R);
  prop_sim_all_k<<<NSTEPS*BB, 256, 0, stream>>>(R, prop_embeds, psa);

  // ---- phase E: step-invariant heavy GEMMs (bf16 out). Clobbers gX/logits (dead). ----
  for (int p=0; p<3; p++)
    mfma_bt_f32_k<1><<<dim3(2,NN/128,1), 256, 0, stream>>>(
        node_attrs + (size_t)p*HH, Ws_property + (size_t)p*HH*HH,
        nullptr, Tf + (size_t)p*HH, 3*HH, HH, 3*HH, HH, HH/32, nullptr);
  mfma_bt_f32_k<1><<<dim3(2,EE/128,1), 256, 0, stream>>>(
      edge_attrs, Ws_property + (size_t)3*HH*HH,
      nullptr, ET, HH, HH, HH, HH, HH/32, nullptr);

  // ---- phase F: 4-step NSM loop, 2 kernels/step ----
  for (int s=0; s<NSTEPS; s++){
    const float* psa_s = psa + (size_t)s*BB*4;
    nsm_scores_k<<<NN/4 + EE/4, 256, 0, stream>>>(
        Tf, ET, R, psa_s, W_state, W_relation, dist, edge_src, edge_dst,
        s_state, s_rel, s);
    nsm_update_k<<<BB, 256, 0, stream>>>(s_state, s_rel, psa_s, dist);
  }

  // ---- phase G: readout ----
  final_agg_k<<<BB, 256, 0, stream>>>(node_attrs, dist, psa + (size_t)3*BB*4, aggregated);
  qa_build_k<<<(BB*2*HH+255)/256, 256, 0, stream>>>(h_buf, aggregated, QA);
  mfma_bt_f32_k<0><<<dim3(16,2,1), 256, 0, stream>>>(QA, lin_W, out, nullptr,
      2*HH, 2*HH, OUTD, OUTD, 2*HH/32, lin_b);
}

// Round 4
// 1248.062 us; speedup vs baseline: 5.0334x; 1.1591x over previous
//
#include <hip/hip_runtime.h>
#include <hip/hip_bf16.h>
#include <math.h>

// Problem constants
#define BB 256
#define LL 16
#define HH 256
#define VV 5000
#define NPG 150
#define DEG 4
#define NSTEPS 4
#define OUTD 2000
#define NN (BB*NPG)      // 38400
#define EE (BB*NPG*DEG)  // 153600
#define BL (BB*LL)       // 4096
#define VPAD 5120        // logits column pad (40*128)
#define KPAD 5024        // Pm K pad (157*32)

// ---------------- helpers ----------------
__device__ __forceinline__ float wred_sum(float v){
  #pragma unroll
  for(int o=32;o;o>>=1) v += __shfl_down(v,o,64);
  return v;
}
__device__ __forceinline__ float wred_max(float v){
  #pragma unroll
  for(int o=32;o;o>>=1) v = fmaxf(v,__shfl_down(v,o,64));
  return v;
}
__device__ __forceinline__ float block_sum256(float v, float* sh){
  v = wred_sum(v);
  __syncthreads();
  if((threadIdx.x&63)==0) sh[threadIdx.x>>6]=v;
  __syncthreads();
  return sh[0]+sh[1]+sh[2]+sh[3];
}
__device__ __forceinline__ float block_max256(float v, float* sh){
  v = wred_max(v);
  __syncthreads();
  if((threadIdx.x&63)==0) sh[threadIdx.x>>6]=v;
  __syncthreads();
  return fmaxf(fmaxf(sh[0],sh[1]),fmaxf(sh[2],sh[3]));
}
__device__ __forceinline__ float eluf(float x){ return x>0.f ? x : expm1f(x); }
__device__ __forceinline__ float sigf(float x){ return 1.f/(1.f+expf(-x)); }
__device__ __forceinline__ float b2f(unsigned short s){
  union{float f; unsigned int u;} x; x.u = ((unsigned int)s)<<16; return x.f;
}
__device__ __forceinline__ unsigned short f2bf_bits(float x){
  union { __hip_bfloat16 h; unsigned short s; } u; u.h = __float2bfloat16(x); return u.s;
}

// async global->LDS 16B (gfx950), lds dest = wave-uniform base + lane*16
__device__ __forceinline__ void async16(void* lds, const void* g){
  __builtin_amdgcn_global_load_lds(
      (const __attribute__((address_space(1))) unsigned int*)g,
      (__attribute__((address_space(3))) unsigned int*)lds, 16, 0, 0);
}

typedef __attribute__((ext_vector_type(8))) short short8;
typedef __attribute__((ext_vector_type(4))) float f32x4;

__device__ __forceinline__ short8 pack8(float4 a, float4 b){
  short8 r;
  r[0]=(short)f2bf_bits(a.x); r[1]=(short)f2bf_bits(a.y);
  r[2]=(short)f2bf_bits(a.z); r[3]=(short)f2bf_bits(a.w);
  r[4]=(short)f2bf_bits(b.x); r[5]=(short)f2bf_bits(b.y);
  r[6]=(short)f2bf_bits(b.z); r[7]=(short)f2bf_bits(b.w);
  return r;
}

// =======================================================================
// MFMA GEMM, C[m,n] = sum_k A[m,k]*Bt[n,k].  128x128 tile, BK=32, 4 waves.
// EPI: 0 = f32 store (+bias, col<Nreal), 1 = bf16 store, 2 = f32 atomicAdd
//      (EPI 2: optional per-row scale rscale[row])
// =======================================================================
template<int EPI>
__global__ __launch_bounds__(256) void mfma_bt_bf16_k(
    const __hip_bfloat16* __restrict__ A, const __hip_bfloat16* __restrict__ Bt,
    float* __restrict__ Cf, __hip_bfloat16* __restrict__ Cb,
    int lda, int ldb, int ldc, int Nreal,
    int kItersTotal, int kPerSplit, const float* __restrict__ bias,
    const float* __restrict__ rscale)
{
  __shared__ __hip_bfloat16 As[128*32];
  __shared__ __hip_bfloat16 Bs[128*32];
  const int bm = blockIdx.y*128, bn = blockIdx.x*128;
  const int tid = threadIdx.x;
  int k0 = blockIdx.z * kPerSplit;
  int k1 = k0 + kPerSplit; if (k1 > kItersTotal) k1 = kItersTotal;
  const int lane = tid & 63, wave = tid >> 6;
  const int quad = lane >> 4, r16 = lane & 15;
  const int wr = wave >> 1, wc = wave & 1;
  f32x4 acc[4][4] = {};
  const int c0 = tid, c1 = tid + 256;
  const int ar0 = c0 >> 2, ak0 = (c0 & 3)*8;
  const int ar1 = c1 >> 2, ak1 = (c1 & 3)*8;
  const __hip_bfloat16* Ab = A + (size_t)bm*lda;
  const __hip_bfloat16* Bb = Bt + (size_t)bn*ldb;
  for (int kk = k0; kk < k1; ++kk){
    const int kb = kk*32;
    async16(&As[c0*8], Ab + (size_t)ar0*lda + kb + ak0);
    async16(&As[c1*8], Ab + (size_t)ar1*lda + kb + ak1);
    async16(&Bs[c0*8], Bb + (size_t)ar0*ldb + kb + ak0);
    async16(&Bs[c1*8], Bb + (size_t)ar1*ldb + kb + ak1);
    __syncthreads();
    short8 av[4], bv[4];
    #pragma unroll
    for (int i=0;i<4;i++){
      av[i] = *(const short8*)&As[(wr*64 + i*16 + r16)*32 + quad*8];
      bv[i] = *(const short8*)&Bs[(wc*64 + i*16 + r16)*32 + quad*8];
    }
    #pragma unroll
    for (int i=0;i<4;i++)
      #pragma unroll
      for (int j=0;j<4;j++)
        acc[i][j] = __builtin_amdgcn_mfma_f32_16x16x32_bf16(av[i], bv[j], acc[i][j], 0,0,0);
    __syncthreads();
  }
  #pragma unroll
  for (int i=0;i<4;i++){
    int row = bm + wr*64 + i*16 + quad*4;
    #pragma unroll
    for (int j=0;j<4;j++){
      int col = bn + wc*64 + j*16 + r16;
      if (col >= Nreal) continue;
      #pragma unroll
      for (int r=0;r<4;r++){
        float v = acc[i][j][r];
        if (EPI==0){ if (bias) v += bias[col]; Cf[(size_t)(row+r)*ldc + col] = v; }
        else if (EPI==1){ Cb[(size_t)(row+r)*ldc + col] = __float2bfloat16(v); }
        else { if (rscale) v *= rscale[row+r]; atomicAdd(&Cf[(size_t)(row+r)*ldc + col], v); }
      }
    }
  }
}

// Same GEMM, f32 global operands, packed bf16 staging (2x float4 -> 1x b128 LDS write)
template<int EPI>
__global__ __launch_bounds__(256) void mfma_bt_f32_k(
    const float* __restrict__ A, const float* __restrict__ Bt,
    float* __restrict__ Cf, __hip_bfloat16* __restrict__ Cb,
    int lda, int ldb, int ldc, int Nreal,
    int kIters, const float* __restrict__ bias)
{
  __shared__ __hip_bfloat16 As[128*32];
  __shared__ __hip_bfloat16 Bs[128*32];
  const int bm = blockIdx.y*128, bn = blockIdx.x*128;
  const int tid = threadIdx.x;
  const int lane = tid & 63, wave = tid >> 6;
  const int quad = lane >> 4, r16 = lane & 15;
  const int wr = wave >> 1, wc = wave & 1;
  f32x4 acc[4][4] = {};
  for (int kk = 0; kk < kIters; ++kk){
    const int kb = kk*32;
    #pragma unroll
    for (int i=0;i<2;i++){
      int c = tid + i*256;
      int row = c >> 2, k0 = (c & 3)*8;
      const float* src = A + (size_t)(bm+row)*lda + kb + k0;
      float4 v0 = *(const float4*)(src);
      float4 v1 = *(const float4*)(src+4);
      *(short8*)&As[row*32 + k0] = pack8(v0, v1);
    }
    #pragma unroll
    for (int i=0;i<2;i++){
      int c = tid + i*256;
      int row = c >> 2, k0 = (c & 3)*8;
      float4 v0 = {0.f,0.f,0.f,0.f}, v1 = {0.f,0.f,0.f,0.f};
      if (bn + row < Nreal){
        const float* src = Bt + (size_t)(bn+row)*ldb + kb + k0;
        v0 = *(const float4*)(src);
        v1 = *(const float4*)(src+4);
      }
      *(short8*)&Bs[row*32 + k0] = pack8(v0, v1);
    }
    __syncthreads();
    short8 av[4], bv[4];
    #pragma unroll
    for (int i=0;i<4;i++){
      av[i] = *(const short8*)&As[(wr*64 + i*16 + r16)*32 + quad*8];
      bv[i] = *(const short8*)&Bs[(wc*64 + i*16 + r16)*32 + quad*8];
    }
    #pragma unroll
    for (int i=0;i<4;i++)
      #pragma unroll
      for (int j=0;j<4;j++)
        acc[i][j] = __builtin_amdgcn_mfma_f32_16x16x32_bf16(av[i], bv[j], acc[i][j], 0,0,0);
    __syncthreads();
  }
  #pragma unroll
  for (int i=0;i<4;i++){
    int row = bm + wr*64 + i*16 + quad*4;
    #pragma unroll
    for (int j=0;j<4;j++){
      int col = bn + wc*64 + j*16 + r16;
      if (col >= Nreal) continue;
      #pragma unroll
      for (int r=0;r<4;r++){
        float v = acc[i][j][r];
        if (EPI==0){ if (bias) v += bias[col]; Cf[(size_t)(row+r)*ldc + col] = v; }
        else { Cb[(size_t)(row+r)*ldc + col] = __float2bfloat16(v); }
      }
    }
  }
}

// Fused logits GEMM + exp epilogue: Pm[r][c] = exp(logit) (unnormalized, bf16),
// row_sum[r] += partial sums (cols 0..VV), e_def[r] = exp(logit[VV]).
__global__ __launch_bounds__(256) void gemm_exp_k(
    const __hip_bfloat16* __restrict__ A, const __hip_bfloat16* __restrict__ Bt,
    __hip_bfloat16* __restrict__ Pm, float* __restrict__ row_sum,
    float* __restrict__ e_def)
{
  __shared__ __hip_bfloat16 As[128*32];
  __shared__ __hip_bfloat16 Bs[128*32];
  const int bm = blockIdx.y*128, bn = blockIdx.x*128;
  const int tid = threadIdx.x;
  const int lane = tid & 63, wave = tid >> 6;
  const int quad = lane >> 4, r16 = lane & 15;
  const int wr = wave >> 1, wc = wave & 1;
  f32x4 acc[4][4] = {};
  const int c0 = tid, c1 = tid + 256;
  const int ar0 = c0 >> 2, ak0 = (c0 & 3)*8;
  const int ar1 = c1 >> 2, ak1 = (c1 & 3)*8;
  const __hip_bfloat16* Ab = A + (size_t)bm*HH;
  const __hip_bfloat16* Bb = Bt + (size_t)bn*HH;
  for (int kk = 0; kk < HH/32; ++kk){
    const int kb = kk*32;
    async16(&As[c0*8], Ab + (size_t)ar0*HH + kb + ak0);
    async16(&As[c1*8], Ab + (size_t)ar1*HH + kb + ak1);
    async16(&Bs[c0*8], Bb + (size_t)ar0*HH + kb + ak0);
    async16(&Bs[c1*8], Bb + (size_t)ar1*HH + kb + ak1);
    __syncthreads();
    short8 av[4], bv[4];
    #pragma unroll
    for (int i=0;i<4;i++){
      av[i] = *(const short8*)&As[(wr*64 + i*16 + r16)*32 + quad*8];
      bv[i] = *(const short8*)&Bs[(wc*64 + i*16 + r16)*32 + quad*8];
    }
    #pragma unroll
    for (int i=0;i<4;i++)
      #pragma unroll
      for (int j=0;j<4;j++)
        acc[i][j] = __builtin_amdgcn_mfma_f32_16x16x32_bf16(av[i], bv[j], acc[i][j], 0,0,0);
    __syncthreads();
  }
  #pragma unroll
  for (int i=0;i<4;i++){
    int rowb = bm + wr*64 + i*16 + quad*4;
    float rsum[4] = {0.f,0.f,0.f,0.f};
    #pragma unroll
    for (int j=0;j<4;j++){
      int col = bn + wc*64 + j*16 + r16;
      #pragma unroll
      for (int r=0;r<4;r++){
        float e = (col <= VV) ? expf(acc[i][j][r]) : 0.f;
        rsum[r] += e;
        if (col < KPAD) Pm[(size_t)(rowb+r)*KPAD + col] = __float2bfloat16(col < VV ? e : 0.f);
        if (col == VV) e_def[rowb+r] = e;
      }
    }
    #pragma unroll
    for (int r=0;r<4;r++){
      float s = rsum[r];
      s += __shfl_xor(s, 1, 64);
      s += __shfl_xor(s, 2, 64);
      s += __shfl_xor(s, 4, 64);
      s += __shfl_xor(s, 8, 64);
      if (r16 == 0) atomicAdd(&row_sum[rowb+r], s);
    }
  }
}

// =======================================================================
// Persistent batch-parallel LSTM: 16 blocks, each owns 16 batch rows; the
// recurrence is independent across batch so no inter-block sync is needed.
// =======================================================================
__global__ __launch_bounds__(256) void lstm_persist_k(
    const float* __restrict__ gX, const __hip_bfloat16* __restrict__ Whh_bf,
    const int* __restrict__ lengths,
    float* __restrict__ h_out, __hip_bfloat16* __restrict__ hbf_out)
{
  __shared__ __hip_bfloat16 hbf[16*264];   // padded stride 264 (bank-spread)
  __shared__ float Gbuf[16*1032];          // padded stride 1032
  __shared__ float cst[16*256];
  __shared__ float hst[16*256];
  __shared__ int   len_s[16];
  const int bg = blockIdx.x, tid = threadIdx.x;
  const int lane = tid & 63, wave = tid >> 6;
  const int quad = lane >> 4, r16 = lane & 15;
  for (int i=tid; i<16*264; i+=256) hbf[i] = __float2bfloat16(0.f);
  for (int i=tid; i<16*256; i+=256){ cst[i]=0.f; hst[i]=0.f; }
  if (tid < 16) len_s[tid] = lengths[bg*16 + tid];
  __syncthreads();
  for (int t=0; t<LL; t++){
    f32x4 acc[16] = {};
    #pragma unroll
    for (int kc=0; kc<8; kc++){
      short8 a = *(const short8*)&hbf[r16*264 + kc*32 + quad*8];
      #pragma unroll
      for (int nt=0; nt<16; nt++){
        int n0 = wave*256 + nt*16;
        short8 b = *(const short8*)&Whh_bf[(size_t)(n0+r16)*HH + kc*32 + quad*8];
        acc[nt] = __builtin_amdgcn_mfma_f32_16x16x32_bf16(a, b, acc[nt], 0,0,0);
      }
    }
    #pragma unroll
    for (int nt=0; nt<16; nt++)
      #pragma unroll
      for (int r=0; r<4; r++)
        Gbuf[(quad*4+r)*1032 + wave*256 + nt*16 + r16] = acc[nt][r];
    __syncthreads();
    #pragma unroll
    for (int i=0; i<16; i++){
      int idx = tid + i*256;
      int b = idx >> 8, hh = idx & 255;
      const float* gx = gX + ((size_t)((bg*16+b)*LL + t))*(4*HH);
      float gi = Gbuf[b*1032 + hh]       + gx[hh];
      float gf = Gbuf[b*1032 + 256 + hh] + gx[256+hh];
      float gc = Gbuf[b*1032 + 512 + hh] + gx[512+hh];
      float go = Gbuf[b*1032 + 768 + hh] + gx[768+hh];
      float cn = sigf(gf)*cst[idx] + sigf(gi)*tanhf(gc);
      float hn = sigf(go)*tanhf(cn);
      if (t < len_s[b]){
        cst[idx] = cn; hst[idx] = hn;
        hbf[b*264 + hh] = __float2bfloat16(hn);
      }
    }
    __syncthreads();
  }
  for (int i=tid; i<16*256; i+=256){
    int b = i >> 8, hh = i & 255;
    h_out[(size_t)(bg*16)*256 + i] = hst[i];
    hbf_out[(size_t)(bg*16)*256 + i] = hbf[b*264 + hh];
  }
}

// Persistent batch-parallel decoder RNN (4 steps + qproj), 16 blocks.
__global__ __launch_bounds__(256) void dec_persist_k(
    const __hip_bfloat16* __restrict__ Qbf, const __hip_bfloat16* __restrict__ Wih_bf,
    const __hip_bfloat16* __restrict__ Whh_bf,
    const float* __restrict__ bih, const float* __restrict__ bhh,
    float* __restrict__ Hins)
{
  __shared__ __hip_bfloat16 qb[16*264];
  __shared__ __hip_bfloat16 xb[16*264];
  __shared__ float qp[16*256];
  __shared__ float Gb[16*264];
  const int bg = blockIdx.x, tid = threadIdx.x;
  const int lane = tid & 63, wave = tid >> 6;
  const int quad = lane >> 4, r16 = lane & 15;
  for (int i=tid; i<16*256; i+=256){
    int b = i >> 8, hh = i & 255;
    qb[b*264+hh] = Qbf[(size_t)(bg*16+b)*256 + hh];
    xb[b*264+hh] = __float2bfloat16(0.f);
  }
  __syncthreads();
  {
    f32x4 acc[4] = {};
    #pragma unroll
    for (int kc=0; kc<8; kc++){
      short8 a = *(const short8*)&qb[r16*264 + kc*32 + quad*8];
      #pragma unroll
      for (int nt=0; nt<4; nt++){
        int n0 = wave*64 + nt*16;
        short8 b = *(const short8*)&Wih_bf[(size_t)(n0+r16)*HH + kc*32 + quad*8];
        acc[nt] = __builtin_amdgcn_mfma_f32_16x16x32_bf16(a, b, acc[nt], 0,0,0);
      }
    }
    #pragma unroll
    for (int nt=0; nt<4; nt++)
      #pragma unroll
      for (int r=0; r<4; r++){
        int row = quad*4+r, col = wave*64 + nt*16 + r16;
        qp[row*256 + col] = acc[nt][r] + bih[col];
      }
  }
  __syncthreads();
  for (int s=0; s<NSTEPS; s++){
    f32x4 acc[4] = {};
    #pragma unroll
    for (int kc=0; kc<8; kc++){
      short8 a = *(const short8*)&xb[r16*264 + kc*32 + quad*8];
      #pragma unroll
      for (int nt=0; nt<4; nt++){
        int n0 = wave*64 + nt*16;
        short8 b = *(const short8*)&Whh_bf[(size_t)(n0+r16)*HH + kc*32 + quad*8];
        acc[nt] = __builtin_amdgcn_mfma_f32_16x16x32_bf16(a, b, acc[nt], 0,0,0);
      }
    }
    #pragma unroll
    for (int nt=0; nt<4; nt++)
      #pragma unroll
      for (int r=0; r<4; r++)
        Gb[(quad*4+r)*264 + wave*64 + nt*16 + r16] = acc[nt][r];
    __syncthreads();
    for (int i=tid; i<16*256; i+=256){
      int b = i >> 8, hh = i & 255;
      float v = fmaxf(qp[i] + Gb[b*264+hh] + bhh[hh], 0.f);
      xb[b*264+hh] = __float2bfloat16(v);
      Hins[(size_t)(bg*16+b)*(NSTEPS*HH) + s*HH + hh] = v;
    }
    __syncthreads();
  }
}

// ---------------- small utility kernels ----------------
__global__ void cvt_bf16_k(const float* __restrict__ src, __hip_bfloat16* __restrict__ dst, int n){
  int i = (blockIdx.x*256 + threadIdx.x)*4;
  if (i >= n) return;
  float4 v = *(const float4*)(src + i);
  dst[i]   = __float2bfloat16(v.x);
  dst[i+1] = __float2bfloat16(v.y);
  dst[i+2] = __float2bfloat16(v.z);
  dst[i+3] = __float2bfloat16(v.w);
}

__global__ void tr_cvt_k(const float* __restrict__ src, __hip_bfloat16* __restrict__ dst, int R, int Ccols){
  int idx = blockIdx.x*256 + threadIdx.x;
  if (idx >= R*Ccols) return;
  int r = idx / Ccols, c = idx % Ccols;
  dst[(size_t)c*R + r] = __float2bfloat16(src[idx]);
}

__global__ void build_cb_k(const float* __restrict__ vocab, const float* __restrict__ de,
                           __hip_bfloat16* __restrict__ Cb){
  int idx = blockIdx.x*256 + threadIdx.x;
  if (idx >= VPAD*HH) return;
  int v = idx >> 8, h = idx & 255;
  float x = (v < VV) ? vocab[(size_t)v*HH + h] : (v == VV ? de[h] : 0.f);
  Cb[idx] = __float2bfloat16(x);
}

__global__ void build_vt_k(const float* __restrict__ vocab, __hip_bfloat16* __restrict__ VT){
  int idx = blockIdx.x*256 + threadIdx.x;
  if (idx >= HH*KPAD) return;
  int h = idx / KPAD, v = idx % KPAD;
  VT[idx] = __float2bfloat16(v < VV ? vocab[(size_t)v*HH + h] : 0.f);
}

__global__ void bsum_k(const float* a, const float* b, float* o){
  int i = blockIdx.x*256 + threadIdx.x;
  if (i < 4*HH) o[i] = a[i] + b[i];
}

__global__ void init_k(float* dist, float* s_rel){
  int idx = blockIdx.x*256 + threadIdx.x;
  if (idx < NN){ dist[idx] = 1.f/150.f; s_rel[idx] = 0.f; }
}

__global__ void zero_k(float* p, int n){
  int idx = blockIdx.x*256 + threadIdx.x;
  if (idx < n) p[idx] = 0.f;
}

__global__ void inv_k(float* p, int n){
  int idx = blockIdx.x*256 + threadIdx.x;
  if (idx < n) p[idx] = 1.f/p[idx];
}

__global__ void vtag_epi_k(float* __restrict__ Vtag, const float* __restrict__ e_def,
                           const float* __restrict__ inv_s, const float* __restrict__ words){
  int r = blockIdx.x, h = threadIdx.x;
  size_t o = (size_t)r*HH + h;
  Vtag[o] += e_def[r]*inv_s[r]*words[o];
}

// attention per graph
__global__ __launch_bounds__(256) void attention_k(const float* __restrict__ Vtag,
                                                   const float* __restrict__ Hins,
                                                   const int* __restrict__ lengths,
                                                   float* __restrict__ R){
  __shared__ float Vl[LL][HH];
  __shared__ float Hn[NSTEPS][HH];
  __shared__ float att[NSTEPS][LL];
  int b = blockIdx.x, tid = threadIdx.x;
  for (int idx=tid; idx<LL*HH; idx+=256){ int l=idx>>8, h=idx&255; Vl[l][h] = Vtag[((size_t)b*LL+l)*HH + h]; }
  for (int idx=tid; idx<NSTEPS*HH; idx+=256){ Hn[idx>>8][idx&255] = Hins[(size_t)b*(NSTEPS*HH) + idx]; }
  __syncthreads();
  if (tid < NSTEPS*LL){
    int n2 = tid>>4, l = tid&15;
    float s = 0.f;
    for (int k=0;k<HH;k++) s += Hn[n2][k]*Vl[l][k];
    att[n2][l] = s;
  }
  __syncthreads();
  int len = lengths[b];
  if (tid < NSTEPS){
    float m = -1e30f;
    for (int l=0;l<len;l++) m = fmaxf(m, att[tid][l]);
    float s = 0.f;
    for (int l=0;l<LL;l++){ float e = (l<len)? expf(att[tid][l]-m) : 0.f; att[tid][l]=e; s+=e; }
    float inv = 1.f/s;
    for (int l=0;l<LL;l++) att[tid][l] *= inv;
  }
  __syncthreads();
  {
    int n2 = tid>>6, h0 = (tid&63)*4;
    float r0=0,r1=0,r2=0,r3=0;
    for (int l=0;l<LL;l++){
      float w = att[n2][l];
      r0 += w*Vl[l][h0]; r1 += w*Vl[l][h0+1]; r2 += w*Vl[l][h0+2]; r3 += w*Vl[l][h0+3];
    }
    float* o = R + (size_t)b*(NSTEPS*HH) + n2*HH + h0;
    o[0]=r0; o[1]=r1; o[2]=r2; o[3]=r3;
  }
}

// prop_sim for ALL steps: psa[s][b][4]
__global__ __launch_bounds__(256) void prop_sim_all_k(const float* __restrict__ R,
                                                      const float* __restrict__ pe,
                                                      float* __restrict__ psa){
  __shared__ float sp[4];
  int gb = blockIdx.x;
  int s = gb >> 8, b = gb & 255;
  int tid = threadIdx.x;
  int p = tid>>6, lane = tid&63;
  const float* instr = R + (size_t)b*(NSTEPS*HH) + s*HH;
  float v = 0.f;
  for (int h=lane; h<HH; h+=64) v += instr[h]*pe[p*HH+h];
  v = wred_sum(v);
  if (lane==0) sp[p] = v;
  __syncthreads();
  if (tid==0){
    float m = fmaxf(fmaxf(sp[0],sp[1]),fmaxf(sp[2],sp[3]));
    float e0=expf(sp[0]-m), e1=expf(sp[1]-m), e2=expf(sp[2]-m), e3=expf(sp[3]-m);
    float ss = e0+e1+e2+e3;
    float* o = psa + (size_t)s*BB*4 + b*4;
    o[0]=e0/ss; o[1]=e1/ss; o[2]=e2/ss; o[3]=e3/ss;
  }
}

// K1: node s_state (wave per node) + edge w[e]-scalar scatter into s_rel (wave per edge)
__global__ __launch_bounds__(256) void nsm_scores_k(
    const __hip_bfloat16* __restrict__ Tf, const __hip_bfloat16* __restrict__ ET,
    const float* __restrict__ R, const float* __restrict__ psa_s,
    const float* __restrict__ W_state, const float* __restrict__ Wr,
    const float* __restrict__ dist, const int* __restrict__ esrc, const int* __restrict__ edst,
    float* __restrict__ s_state, float* __restrict__ s_rel, int step)
{
  const int wave = threadIdx.x >> 6, lane = threadIdx.x & 63;
  const int h0 = lane*4;
  if (blockIdx.x < NN/4){
    int n = blockIdx.x*4 + wave;
    int g = n / NPG;
    const float* instr = R + (size_t)g*(NSTEPS*HH) + step*HH;
    float ps0 = psa_s[g*4], ps1 = psa_s[g*4+1], ps2 = psa_s[g*4+2];
    const unsigned short* t = (const unsigned short*)(Tf + (size_t)n*(3*HH));
    ushort4 t0 = *(const ushort4*)(t + h0);
    ushort4 t1 = *(const ushort4*)(t + HH + h0);
    ushort4 t2 = *(const ushort4*)(t + 2*HH + h0);
    float4 iv = *(const float4*)(instr + h0);
    float4 wv = *(const float4*)(W_state + h0);
    float acc;
    acc  = eluf(iv.x*(ps0*b2f(t0.x)+ps1*b2f(t1.x)+ps2*b2f(t2.x)))*wv.x;
    acc += eluf(iv.y*(ps0*b2f(t0.y)+ps1*b2f(t1.y)+ps2*b2f(t2.y)))*wv.y;
    acc += eluf(iv.z*(ps0*b2f(t0.z)+ps1*b2f(t1.z)+ps2*b2f(t2.z)))*wv.z;
    acc += eluf(iv.w*(ps0*b2f(t0.w)+ps1*b2f(t1.w)+ps2*b2f(t2.w)))*wv.w;
    acc = wred_sum(acc);
    if (lane==0) s_state[n] = acc;
  } else {
    int e = (blockIdx.x - NN/4)*4 + wave;
    int b = e / (NPG*DEG);
    const float* instr = R + (size_t)b*(NSTEPS*HH) + step*HH;
    const unsigned short* et = (const unsigned short*)(ET + (size_t)e*HH);
    ushort4 ev = *(const ushort4*)(et + h0);
    float4 iv = *(const float4*)(instr + h0);
    float4 wv = *(const float4*)(Wr + h0);
    float acc;
    acc  = eluf(iv.x*b2f(ev.x))*wv.x;
    acc += eluf(iv.y*b2f(ev.y))*wv.y;
    acc += eluf(iv.z*b2f(ev.z))*wv.z;
    acc += eluf(iv.w*b2f(ev.w))*wv.w;
    acc = wred_sum(acc);
    if (lane==0) atomicAdd(&s_rel[edst[e]], dist[esrc[e]]*acc);
  }
}

// K2: per-graph — both segment softmaxes + dist update; zeroes s_rel for next step
__global__ __launch_bounds__(256) void nsm_update_k(
    const float* __restrict__ s_state, float* __restrict__ s_rel,
    const float* __restrict__ psa_s, float* __restrict__ dist)
{
  __shared__ float sh[4];
  int b = blockIdx.x, i = threadIdx.x;
  bool ok = (i < NPG);
  float ss = ok ? s_state[b*NPG + i] : -1e30f;
  float sr = ok ? s_rel[b*NPG + i]   : -1e30f;
  float m1 = block_max256(ss, sh);
  float e1 = ok ? expf(ss - m1) : 0.f;
  float d1 = block_sum256(e1, sh);
  float m2 = block_max256(sr, sh);
  float e2 = ok ? expf(sr - m2) : 0.f;
  float d2 = block_sum256(e2, sh);
  if (ok){
    float pst = e1/d1, prl = e2/d2;
    float r = psa_s[b*4+3];
    dist[b*NPG + i] = r*prl + (1.f-r)*pst;
    s_rel[b*NPG + i] = 0.f;
  }
}

__global__ __launch_bounds__(256) void final_agg_k(const float* __restrict__ na, const float* __restrict__ dist,
                                                   const float* __restrict__ ps, float* __restrict__ aggregated){
  int b = blockIdx.x, h = threadIdx.x;
  float ps0 = ps[b*4+0], ps1 = ps[b*4+1], ps2 = ps[b*4+2];
  float acc = 0.f;
  for (int i=0;i<NPG;i++){
    int n = b*NPG + i;
    float d = dist[n];
    const float* a = na + (size_t)n*(3*HH);
    acc += d*(ps0*a[h] + ps1*a[HH+h] + ps2*a[2*HH+h]);
  }
  aggregated[b*HH + h] = acc;
}

__global__ void qa_build_k(const float* __restrict__ Q, const float* __restrict__ aggregated,
                           float* __restrict__ QA){
  int idx = blockIdx.x*256 + threadIdx.x;
  if (idx >= BB*2*HH) return;
  int b = idx >> 9, k = idx & 511;
  QA[idx] = (k < HH) ? Q[b*HH + k] : aggregated[b*HH + (k-HH)];
}

// ---------------- host ----------------
extern "C" void kernel_launch(void* const* d_in, const int* in_sizes, int n_in,
                              void* d_out, int out_size, void* d_ws, size_t ws_size,
                              hipStream_t stream) {
  (void)in_sizes; (void)n_in; (void)out_size; (void)ws_size;
  const float* questions     = (const float*)d_in[0];
  const float* node_attrs    = (const float*)d_in[1];
  const float* edge_attrs    = (const float*)d_in[2];
  const float* vocab         = (const float*)d_in[3];
  const float* default_embed = (const float*)d_in[4];
  const float* W_norm        = (const float*)d_in[5];
  const float* lstm_Wih      = (const float*)d_in[6];   // (1024,256) row-major == Bt
  const float* lstm_Whh      = (const float*)d_in[7];   // (1024,256) row-major == Bt
  const float* lstm_bih      = (const float*)d_in[8];
  const float* lstm_bhh      = (const float*)d_in[9];
  const float* rnn_Wih       = (const float*)d_in[10];  // (256,256) row-major == Bt
  const float* rnn_Whh       = (const float*)d_in[11];
  const float* rnn_bih       = (const float*)d_in[12];
  const float* rnn_bhh       = (const float*)d_in[13];
  const float* prop_embeds   = (const float*)d_in[14];
  const float* Ws_property   = (const float*)d_in[15];
  const float* W_state       = (const float*)d_in[16];
  const float* W_relation    = (const float*)d_in[17];
  const float* lin_W         = (const float*)d_in[18];  // (2000,512) row-major == Bt
  const float* lin_b         = (const float*)d_in[19];
  const int*   lengths       = (const int*)d_in[20];
  const int*   edge_src      = (const int*)d_in[23];
  const int*   edge_dst      = (const int*)d_in[24];
  float* out = (float*)d_out;

  char* base = (char*)d_ws;
  size_t off = 0;
  auto alloc = [&](size_t nbytes)->void*{
    void* p = base + off;
    off += (nbytes + 255) & ~(size_t)255;
    return p;
  };

  __hip_bfloat16* qbf     = (__hip_bfloat16*)alloc((size_t)BL*HH*2);
  __hip_bfloat16* WnT_bf  = (__hip_bfloat16*)alloc((size_t)HH*HH*2);
  __hip_bfloat16* xw_bf   = (__hip_bfloat16*)alloc((size_t)BL*HH*2);
  __hip_bfloat16* Cbv     = (__hip_bfloat16*)alloc((size_t)VPAD*HH*2);
  __hip_bfloat16* vT_bf   = (__hip_bfloat16*)alloc((size_t)HH*KPAD*2);
  __hip_bfloat16* Whh_bf  = (__hip_bfloat16*)alloc((size_t)4*HH*HH*2);
  __hip_bfloat16* rWih_bf = (__hip_bfloat16*)alloc((size_t)HH*HH*2);
  __hip_bfloat16* rWhh_bf = (__hip_bfloat16*)alloc((size_t)HH*HH*2);
  __hip_bfloat16* h_bf    = (__hip_bfloat16*)alloc((size_t)BB*HH*2);
  float* e_def    = (float*)alloc((size_t)BL*4);
  float* row_sum  = (float*)alloc((size_t)BL*4);
  float* Vtag     = (float*)alloc((size_t)BL*HH*4);
  float* bsum     = (float*)alloc((size_t)4*HH*4);
  float* h_buf    = (float*)alloc((size_t)BB*HH*4);
  float* Hins     = (float*)alloc((size_t)BB*NSTEPS*HH*4);
  float* R        = (float*)alloc((size_t)BB*NSTEPS*HH*4);
  float* psa      = (float*)alloc((size_t)NSTEPS*BB*4*4);
  float* s_state  = (float*)alloc((size_t)NN*4);
  float* s_rel    = (float*)alloc((size_t)NN*4);
  float* dist     = (float*)alloc((size_t)NN*4);
  float* aggregated = (float*)alloc((size_t)BB*HH*4);
  float* QA       = (float*)alloc((size_t)BB*2*HH*4);
  __hip_bfloat16* Pm_bf = (__hip_bfloat16*)alloc((size_t)BL*KPAD*2);
  // Tf region (59MB bf16); gX (16.8MB f32) aliases its start (disjoint in time)
  char*  TfR      = (char*)alloc((size_t)NN*3*HH*2);
  __hip_bfloat16* Tf = (__hip_bfloat16*)TfR;
  float* gX          = (float*)TfR;
  __hip_bfloat16* ET = (__hip_bfloat16*)alloc((size_t)EE*HH*2);

  // ---- setup ----
  init_k<<<(NN+255)/256, 256, 0, stream>>>(dist, s_rel);
  cvt_bf16_k<<<(BL*HH/4+255)/256, 256, 0, stream>>>(questions, qbf, BL*HH);
  tr_cvt_k<<<(HH*HH+255)/256, 256, 0, stream>>>(W_norm, WnT_bf, HH, HH);
  build_cb_k<<<(VPAD*HH+255)/256, 256, 0, stream>>>(vocab, default_embed, Cbv);
  build_vt_k<<<(HH*KPAD+255)/256, 256, 0, stream>>>(vocab, vT_bf);
  cvt_bf16_k<<<(4*HH*HH/4+255)/256, 256, 0, stream>>>(lstm_Whh, Whh_bf, 4*HH*HH);
  cvt_bf16_k<<<(HH*HH/4+255)/256, 256, 0, stream>>>(rnn_Wih, rWih_bf, HH*HH);
  cvt_bf16_k<<<(HH*HH/4+255)/256, 256, 0, stream>>>(rnn_Whh, rWhh_bf, HH*HH);
  bsum_k<<<(4*HH+255)/256, 256, 0, stream>>>(lstm_bih, lstm_bhh, bsum);
  zero_k<<<(BL+255)/256, 256, 0, stream>>>(row_sum, BL);
  zero_k<<<(BL*HH+255)/256, 256, 0, stream>>>(Vtag, BL*HH);

  // ---- phase A: word embedding ----
  mfma_bt_bf16_k<1><<<dim3(2,32,1), 256, 0, stream>>>(qbf, WnT_bf, nullptr, xw_bf,
      HH, HH, HH, HH, HH/32, HH/32, nullptr, nullptr);
  gemm_exp_k<<<dim3(VPAD/128, BL/128, 1), 256, 0, stream>>>(xw_bf, Cbv, Pm_bf, row_sum, e_def);
  inv_k<<<(BL+255)/256, 256, 0, stream>>>(row_sum, BL);
  mfma_bt_bf16_k<2><<<dim3(HH/128, BL/128, 8), 256, 0, stream>>>(
      Pm_bf, vT_bf, Vtag, nullptr, KPAD, KPAD, HH, HH, KPAD/32, 20, nullptr, row_sum);
  vtag_epi_k<<<BL, HH, 0, stream>>>(Vtag, e_def, row_sum, questions);

  // ---- phase B: LSTM encoder ----
  mfma_bt_f32_k<0><<<dim3(8,32,1), 256, 0, stream>>>(Vtag, lstm_Wih, gX, nullptr,
      HH, HH, 4*HH, 4*HH, HH/32, bsum);
  lstm_persist_k<<<16, 256, 0, stream>>>(gX, Whh_bf, lengths, h_buf, h_bf);

  // ---- phase C: decoder RNN ----
  dec_persist_k<<<16, 256, 0, stream>>>(h_bf, rWih_bf, rWhh_bf, rnn_bih, rnn_bhh, Hins);

  // ---- phase D: attention -> R; prop_sim for all steps ----
  attention_k<<<BB, 256, 0, stream>>>(Vtag, Hins, lengths, R);
  prop_sim_all_k<<<NSTEPS*BB, 256, 0, stream>>>(R, prop_embeds, psa);

  // ---- phase E: step-invariant heavy GEMMs (bf16 out). Clobbers gX (dead). ----
  for (int p=0; p<3; p++)
    mfma_bt_f32_k<1><<<dim3(2,NN/128,1), 256, 0, stream>>>(
        node_attrs + (size_t)p*HH, Ws_property + (size_t)p*HH*HH,
        nullptr, Tf + (size_t)p*HH, 3*HH, HH, 3*HH, HH, HH/32, nullptr);
  mfma_bt_f32_k<1><<<dim3(2,EE/128,1), 256, 0, stream>>>(
      edge_attrs, Ws_property + (size_t)3*HH*HH,
      nullptr, ET, HH, HH, HH, HH, HH/32, nullptr);

  // ---- phase F: 4-step NSM loop ----
  for (int s=0; s<NSTEPS; s++){
    const float* psa_s = psa + (size_t)s*BB*4;
    nsm_scores_k<<<NN/4 + EE/4, 256, 0, stream>>>(
        Tf, ET, R, psa_s, W_state, W_relation, dist, edge_src, edge_dst,
        s_state, s_rel, s);
    nsm_update_k<<<BB, 256, 0, stream>>>(s_state, s_rel, psa_s, dist);
  }

  // ---- phase G: readout ----
  final_agg_k<<<BB, 256, 0, stream>>>(node_attrs, dist, psa + (size_t)3*BB*4, aggregated);
  qa_build_k<<<(BB*2*HH+255)/256, 256, 0, stream>>>(h_buf, aggregated, QA);
  mfma_bt_f32_k<0><<<dim3(16,2,1), 256, 0, stream>>>(QA, lin_W, out, nullptr,
      2*HH, 2*HH, OUTD, OUTD, 2*HH/32, lin_b);
}